// Round 2
// baseline (350.215 us; speedup 1.0000x reference)
//
#include <hip/hip_runtime.h>
#include <hip/hip_bf16.h>

#define B_   4
#define LQ_  128
#define LF_  64
#define NW_  2
#define NFR_ 8
#define E_   128
#define D_   128
#define V_   64
#define NWF_ (NW_*NFR_)            // 16
#define NROW_Q (B_*LQ_)            // 512
#define NROW_F (B_*NW_*NFR_*LF_)   // 4096

using bf16 = __hip_bfloat16;
typedef unsigned short u16;
typedef unsigned int   u32;

// ---- workspace layout (float-index units) ----
// flag  @ 0         (int)
// qp    @ 4         [B*LQ][D] f32           65536
// qatt  @ 65540     [B*LQ][V] f32           32768
// e2    @ 98308     [B*NWF][LQ] f32          8192
// fp16  @ 106500    [B*NWF*LF][D] u16 (bf16 bits), 524288 u16 = 262144 floats
// total = 368644 floats = 1.47 MB
#define WS_FLAG 0
#define WS_QP   4
#define WS_QATT 65540
#define WS_E2   98308
#define WS_FP16 106500

// ---- out layout (element units; element = u16 or f32 per flag) ----
#define OUT_FRAGCODE  0       // (B,NW,NFR,D)   8192
#define OUT_QUERYCODE 8192    // (B,NW,NFR,D)   8192
#define OUT_SELFATT   16384   // (B,NW,NFR,LF)  4096
#define OUT_QFGATE    20480   // (B,16,LQ)      8192
#define OUT_QUERY     28672   // (B,LQ,D)       65536

__device__ __forceinline__ float us2f(u16 v) { return __uint_as_float((u32)v << 16); }
__device__ __forceinline__ u16 f2b_raw(float f) {
    u32 u = __float_as_uint(f);
    return (u16)((u + 0x7fffu + ((u >> 16) & 1u)) >> 16);
}
template<bool BF> __device__ __forceinline__ float LD(const void* p, int i) {
    return BF ? us2f(((const u16*)p)[i]) : ((const float*)p)[i];
}
template<bool BF> __device__ __forceinline__ void ST(void* p, int i, float v) {
    if (BF) ((u16*)p)[i] = f2b_raw(v); else ((float*)p)[i] = v;
}

// Kernel 0: dtype detection. query_mask is all-ones; first u16 of fp32 1.0f
// is 0x0000, of bf16 1.0 is 0x3F80.
__global__ void k_flag(const void* qmask, float* ws) {
    ((int*)ws)[WS_FLAG] = (((const u16*)qmask)[0] == 0x3F80u) ? 1 : 0;
}

// Kernel 1: projection of query+fragment rows; q_att for query rows.
template<bool BF>
__device__ __forceinline__ void proj_body(
    const void* query, const void* fragment,
    const void* projW, const void* projB, const void* qattW,
    float* ws, void* out)
{
    __shared__ float sx[E_];
    __shared__ float sy[D_];
    int r = blockIdx.x;
    int t = threadIdx.x;
    sx[t] = (r < NROW_Q) ? LD<BF>(query, r * E_ + t)
                         : LD<BF>(fragment, (r - NROW_Q) * E_ + t);
    __syncthreads();
    float y = LD<BF>(projB, t);
    #pragma unroll 8
    for (int e = 0; e < E_; ++e)
        y += sx[e] * LD<BF>(projW, e * D_ + t);
    if (r < NROW_Q) {
        ws[WS_QP + r * D_ + t] = y;
        ST<BF>(out, OUT_QUERY + r * D_ + t, y);
    } else {
        u16* fp16 = (u16*)(ws + WS_FP16);
        fp16[(size_t)(r - NROW_Q) * D_ + t] = f2b_raw(y);
    }
    sy[t] = y;
    __syncthreads();
    if (r < NROW_Q && t < V_) {
        float a = 0.f;
        #pragma unroll 8
        for (int d = 0; d < D_; ++d)
            a += sy[d] * LD<BF>(qattW, d * V_ + t);
        ws[WS_QATT + r * V_ + t] = a;
    }
}
__global__ __launch_bounds__(128) void k_proj(
    const void* query, const void* fragment,
    const void* projW, const void* projB, const void* qattW,
    float* ws, void* out)
{
    if (((const int*)ws)[WS_FLAG]) proj_body<true >(query, fragment, projW, projB, qattW, ws, out);
    else                           proj_body<false>(query, fragment, projW, projB, qattW, ws, out);
}

// Kernel 2: fragment self-attention softmax + frag_code. One block per (b,w,f).
template<bool BF>
__device__ __forceinline__ void fragatt_body(
    const void* saW, const void* fmask, const float* ws, void* out)
{
    __shared__ float s_att[LF_];
    __shared__ float s_sum;
    int g = blockIdx.x;             // b*16 + w*8 + f
    int w = (g >> 3) & (NW_ - 1);
    int t = threadIdx.x;
    const u16* fp = (const u16*)(ws + WS_FP16) + (size_t)g * (LF_ * D_);
    if (t < LF_) {
        float lg = 0.f;
        #pragma unroll 8
        for (int d = 0; d < D_; ++d)
            lg += us2f(fp[t * D_ + d]) * LD<BF>(saW, w * D_ + d);
        s_att[t] = expf(lg) * LD<BF>(fmask, g * LF_ + t);
    }
    __syncthreads();
    if (t == 0) {
        float s = 0.f;
        for (int l = 0; l < LF_; ++l) s += s_att[l];
        s_sum = s + 1e-7f;
    }
    __syncthreads();
    float inv = 1.0f / s_sum;
    if (t < LF_) {
        float a = s_att[t] * inv;
        s_att[t] = a;
        ST<BF>(out, OUT_SELFATT + g * LF_ + t, a);
    }
    __syncthreads();
    float fc = 0.f;
    #pragma unroll 8
    for (int l = 0; l < LF_; ++l)
        fc += us2f(fp[l * D_ + t]) * s_att[l];
    ST<BF>(out, OUT_FRAGCODE + g * D_ + t, fc);
}
__global__ __launch_bounds__(128) void k_fragatt(
    const void* saW, const void* fmask, const float* ws, void* out)
{
    if (((const int*)ws)[WS_FLAG]) fragatt_body<true >(saW, fmask, ws, out);
    else                           fragatt_body<false>(saW, fmask, ws, out);
}

// Kernel 3: qf pass. Block = (b,wf, q-tile of 16), 256 threads.
// C'[l,v] = sum_d fp[l,d] * (qp[q,d]*W3[d,v] + Wf[d,v])   (f_att folded in)
// qf[q,v] = max_l C'[l,v] + q_att[q,v]; then gate / e2 reductions over v.
template<bool BF>
__device__ __forceinline__ void qf_body(
    const void* qfW, const void* fattW,
    const void* gatew, const void* valw, const void* qmask,
    float* ws, void* out)
{
    __shared__ u16   s_fp[LF_][132];   // bf16 bits, padded
    __shared__ float s_wq[V_][132];
    __shared__ float s_qrow[D_];
    __shared__ float s_qf[V_];
    __shared__ float s_gw[V_], s_vw[V_];

    int blk = blockIdx.x;
    int bwf = blk >> 3;            // 0..63  (= b*16 + wf)
    int qt  = blk & 7;
    int b   = bwf >> 4;
    int t   = threadIdx.x;
    float* wse2 = ws + WS_E2;

    if (t < V_) { s_gw[t] = LD<BF>(gatew, t); s_vw[t] = LD<BF>(valw, t); }

    // stage fp tile from ws bf16 region (u32 = 2 elements per load)
    {
        const u32* fpv = (const u32*)((const u16*)(ws + WS_FP16) + (size_t)bwf * (LF_ * D_));
        #pragma unroll
        for (int k = 0; k < 16; ++k) {
            int i = t + 256 * k;       // 0..4095
            u32 v = fpv[i];
            int l = i >> 6;            // 64 u32 per row
            int d = (i & 63) << 1;
            *(u32*)&s_fp[l][d] = v;
        }
    }
    // preload W3 (qf_att_W) and Wf (f_att_W) into registers, coalesced
    float w3r[32], wfr[32];
    #pragma unroll
    for (int k = 0; k < 32; ++k) {
        int i = t + 256 * k;
        w3r[k] = LD<BF>(qfW, i);
        wfr[k] = LD<BF>(fattW, i);
    }
    __syncthreads();

    int lg = t & 15;    // l-group: l = lg*4 + i
    int vg = t >> 4;    // v-group: v = vg*4 + j
    int dq = t >> 6;    // wq-build d base
    int vv = t & 63;    // wq-build v index

    for (int qi = 0; qi < 16; ++qi) {
        int q = qt * 16 + qi;
        __syncthreads();   // previous iteration's reads of s_wq/s_qrow done
        if (t < D_) s_qrow[t] = ws[WS_QP + (size_t)(b * LQ_ + q) * D_ + t];
        __syncthreads();
        #pragma unroll
        for (int k = 0; k < 32; ++k) {
            int d = dq + 4 * k;
            s_wq[vv][d] = s_qrow[d] * w3r[k] + wfr[k];
        }
        __syncthreads();

        float acc[4][4];
        #pragma unroll
        for (int i = 0; i < 4; ++i)
            #pragma unroll
            for (int j = 0; j < 4; ++j) acc[i][j] = 0.f;

        #pragma unroll 2
        for (int dc = 0; dc < 32; ++dc) {
            int d = dc * 4;
            float a[4][4];
            #pragma unroll
            for (int i = 0; i < 4; ++i) {
                uint2 rp = *(const uint2*)&s_fp[lg * 4 + i][d];
                a[i][0] = __uint_as_float(rp.x << 16);
                a[i][1] = __uint_as_float(rp.x & 0xffff0000u);
                a[i][2] = __uint_as_float(rp.y << 16);
                a[i][3] = __uint_as_float(rp.y & 0xffff0000u);
            }
            #pragma unroll
            for (int j = 0; j < 4; ++j) {
                float4 wv = *(const float4*)&s_wq[vg * 4 + j][d];
                #pragma unroll
                for (int i = 0; i < 4; ++i) {
                    acc[i][j] += a[i][0] * wv.x + a[i][1] * wv.y
                               + a[i][2] * wv.z + a[i][3] * wv.w;
                }
            }
        }
        // max over l: local 4, then across lg lanes (xor bits 0..3)
        #pragma unroll
        for (int j = 0; j < 4; ++j) {
            float m = fmaxf(fmaxf(acc[0][j], acc[1][j]), fmaxf(acc[2][j], acc[3][j]));
            m = fmaxf(m, __shfl_xor(m, 1, 64));
            m = fmaxf(m, __shfl_xor(m, 2, 64));
            m = fmaxf(m, __shfl_xor(m, 4, 64));
            m = fmaxf(m, __shfl_xor(m, 8, 64));
            if (lg == 0) s_qf[vg * 4 + j] = m;
        }
        __syncthreads();
        if (t < V_) {   // wave 0 only
            float qf = s_qf[t] + ws[WS_QATT + (size_t)(b * LQ_ + q) * V_ + t];
            float gp = qf * s_gw[t];
            float ep = qf * s_vw[t];
            #pragma unroll
            for (int off = 32; off >= 1; off >>= 1) {
                gp += __shfl_xor(gp, off, 64);
                ep += __shfl_xor(ep, off, 64);
            }
            if (t == 0) {
                float qm = LD<BF>(qmask, b * LQ_ + q);
                float g = (1.0f / (1.0f + expf(-gp))) * qm;
                ST<BF>(out, OUT_QFGATE + bwf * LQ_ + q, g);
                wse2[bwf * LQ_ + q] = expf(ep) * qm;
            }
        }
    }
}
__global__ __launch_bounds__(256) void k_qf(
    const void* qfW, const void* fattW,
    const void* gatew, const void* valw, const void* qmask,
    float* ws, void* out)
{
    if (((const int*)ws)[WS_FLAG]) qf_body<true >(qfW, fattW, gatew, valw, qmask, ws, out);
    else                           qf_body<false>(qfW, fattW, gatew, valw, qmask, ws, out);
}

// Kernel 4: softmax of e2 over LQ per (b,wf) + query_code.
template<bool BF>
__device__ __forceinline__ void qcode_body(const float* ws, void* out)
{
    __shared__ float s_n[LQ_];
    __shared__ float s_sum;
    int bwf = blockIdx.x;
    int b = bwf >> 4;
    int t = threadIdx.x;
    float e = ws[WS_E2 + bwf * LQ_ + t];
    s_n[t] = e;
    __syncthreads();
    if (t == 0) {
        float s = 0.f;
        for (int q = 0; q < LQ_; ++q) s += s_n[q];
        s_sum = s + 1e-7f;
    }
    __syncthreads();
    float inv = 1.0f / s_sum;
    s_n[t] = e * inv;
    __syncthreads();
    float qc = 0.f;
    #pragma unroll 8
    for (int q = 0; q < LQ_; ++q)
        qc += ws[WS_QP + (size_t)(b * LQ_ + q) * D_ + t] * s_n[q];
    ST<BF>(out, OUT_QUERYCODE + bwf * D_ + t, qc);
}
__global__ __launch_bounds__(128) void k_qcode(const float* ws, void* out)
{
    if (((const int*)ws)[WS_FLAG]) qcode_body<true >(ws, out);
    else                           qcode_body<false>(ws, out);
}

extern "C" void kernel_launch(void* const* d_in, const int* in_sizes, int n_in,
                              void* d_out, int out_size, void* d_ws, size_t ws_size,
                              hipStream_t stream)
{
    const void* query    = d_in[0];
    const void* fragment = d_in[1];
    const void* qmask    = d_in[2];
    const void* fmask    = d_in[3];
    const void* projW    = d_in[4];
    const void* projB    = d_in[5];
    const void* saW      = d_in[6];
    const void* qattW    = d_in[7];
    const void* fattW    = d_in[8];
    const void* qfW      = d_in[9];
    const void* gatew    = d_in[10];
    const void* valw     = d_in[11];
    float* ws = (float*)d_ws;

    hipLaunchKernelGGL(k_flag, dim3(1), dim3(1), 0, stream, qmask, ws);
    hipLaunchKernelGGL(k_proj, dim3(NROW_Q + NROW_F), dim3(128), 0, stream,
                       query, fragment, projW, projB, qattW, ws, d_out);
    hipLaunchKernelGGL(k_fragatt, dim3(B_ * NW_ * NFR_), dim3(128), 0, stream,
                       saW, fmask, ws, d_out);
    hipLaunchKernelGGL(k_qf, dim3(512), dim3(256), 0, stream,
                       qfW, fattW, gatew, valw, qmask, ws, d_out);
    hipLaunchKernelGGL(k_qcode, dim3(B_ * NWF_), dim3(128), 0, stream,
                       ws, d_out);
}

// Round 3
// 133.111 us; speedup vs baseline: 2.6310x; 2.6310x over previous
//
#include <hip/hip_runtime.h>
#include <hip/hip_bf16.h>

#define B_   4
#define LQ_  128
#define LF_  64
#define NW_  2
#define NFR_ 8
#define E_   128
#define D_   128
#define V_   64
#define NWF_ (NW_*NFR_)            // 16
#define NROW_Q (B_*LQ_)            // 512
#define NROW_F (B_*NW_*NFR_*LF_)   // 4096

using bf16 = __hip_bfloat16;
typedef unsigned short u16;
typedef unsigned int   u32;
typedef __attribute__((ext_vector_type(8))) short  bf16x8;
typedef __attribute__((ext_vector_type(4))) float  f32x4;
typedef __attribute__((ext_vector_type(4))) u32    u32x4;

// ---- workspace layout (float-index units) ----
// flag   @ 0        4
// qp     @ 4        [B*LQ][D] f32          65536
// qatt   @ 65540    [B*LQ][V] f32          32768
// e2     @ 98308    [B*NWF][LQ] f32         8192
// fatt16 @ 106500   [64][64][64] u16       262144 u16 = 131072 f
// fp16   @ 237572   [4096][128] u16        524288 u16 = 262144 f
// total = 499716 floats ~= 2.0 MB
#define WS_FLAG   0
#define WS_QP     4
#define WS_QATT   65540
#define WS_E2     98308
#define WS_FATT16 106500
#define WS_FP16   237572

// ---- out layout (element units) ----
#define OUT_FRAGCODE  0       // (B,NW,NFR,D)   8192
#define OUT_QUERYCODE 8192    // (B,NW,NFR,D)   8192
#define OUT_SELFATT   16384   // (B,NW,NFR,LF)  4096
#define OUT_QFGATE    20480   // (B,16,LQ)      8192
#define OUT_QUERY     28672   // (B,LQ,D)       65536

__device__ __forceinline__ float us2f(u16 v) { return __uint_as_float((u32)v << 16); }
__device__ __forceinline__ float lo2f(u32 v) { return __uint_as_float(v << 16); }
__device__ __forceinline__ float hi2f(u32 v) { return __uint_as_float(v & 0xffff0000u); }
__device__ __forceinline__ u16 f2b_raw(float f) {
    u32 u = __float_as_uint(f);
    return (u16)((u + 0x7fffu + ((u >> 16) & 1u)) >> 16);
}
// pack two f32 into (bf16(hi)<<16)|bf16(lo), truncating: 1 v_perm_b32
__device__ __forceinline__ u32 pk2(float hi, float lo) {
    return __builtin_amdgcn_perm(__float_as_uint(hi), __float_as_uint(lo), 0x07060302u);
}
template<bool BF> __device__ __forceinline__ float LD(const void* p, int i) {
    return BF ? us2f(((const u16*)p)[i]) : ((const float*)p)[i];
}
template<bool BF> __device__ __forceinline__ void ST(void* p, int i, float v) {
    if (BF) ((u16*)p)[i] = f2b_raw(v); else ((float*)p)[i] = v;
}
template<bool BF> __device__ __forceinline__ u16 LDB(const void* p, int i) {
    return BF ? ((const u16*)p)[i] : f2b_raw(((const float*)p)[i]);
}

// Kernel 0: dtype detection (query_mask is all ones; u16[0] of fp32 1.0f is 0).
__global__ void k_flag(const void* qmask, float* ws) {
    ((int*)ws)[WS_FLAG] = (((const u16*)qmask)[0] == 0x3F80u) ? 1 : 0;
}

// ---------------- Kernel 1: projection + q_att ----------------
template<bool BF>
__device__ __forceinline__ void proj_body(
    const void* query, const void* fragment,
    const void* projW, const void* projB, const void* qattW,
    float* ws, void* out, float* sx, float* sy)
{
    int r = blockIdx.x;
    int t = threadIdx.x;
    sx[t] = (r < NROW_Q) ? LD<BF>(query, r * E_ + t)
                         : LD<BF>(fragment, (r - NROW_Q) * E_ + t);
    __syncthreads();
    float y = LD<BF>(projB, t);
    #pragma unroll 8
    for (int e = 0; e < E_; ++e)
        y += sx[e] * LD<BF>(projW, e * D_ + t);
    if (r < NROW_Q) {
        ws[WS_QP + r * D_ + t] = y;
        ST<BF>(out, OUT_QUERY + r * D_ + t, y);
    } else {
        u16* fp16 = (u16*)(ws + WS_FP16);
        fp16[(size_t)(r - NROW_Q) * D_ + t] = f2b_raw(y);
    }
    sy[t] = y;
    __syncthreads();
    if (r < NROW_Q && t < V_) {
        float a = 0.f;
        #pragma unroll 8
        for (int d = 0; d < D_; ++d)
            a += sy[d] * LD<BF>(qattW, d * V_ + t);
        ws[WS_QATT + r * V_ + t] = a;
    }
}
__global__ __launch_bounds__(128) void k_proj(
    const void* query, const void* fragment,
    const void* projW, const void* projB, const void* qattW,
    float* ws, void* out)
{
    __shared__ float sx[E_];
    __shared__ float sy[D_];
    if (((const int*)ws)[WS_FLAG]) proj_body<true >(query, fragment, projW, projB, qattW, ws, out, sx, sy);
    else                           proj_body<false>(query, fragment, projW, projB, qattW, ws, out, sx, sy);
}

// ---------------- Kernel 2: fragment softmax + frag_code ----------------
template<bool BF>
__device__ __forceinline__ void fragatt_body(
    const void* saW, const void* fmask, const float* ws, void* out,
    float* s_att, float* s_sum)
{
    int g = blockIdx.x;             // b*16 + w*8 + f
    int w = (g >> 3) & (NW_ - 1);
    int t = threadIdx.x;
    const u16* fp = (const u16*)(ws + WS_FP16) + (size_t)g * (LF_ * D_);
    if (t < LF_) {
        float lg = 0.f;
        #pragma unroll 8
        for (int d = 0; d < D_; ++d)
            lg += us2f(fp[t * D_ + d]) * LD<BF>(saW, w * D_ + d);
        s_att[t] = expf(lg) * LD<BF>(fmask, g * LF_ + t);
    }
    __syncthreads();
    if (t == 0) {
        float s = 0.f;
        for (int l = 0; l < LF_; ++l) s += s_att[l];
        *s_sum = s + 1e-7f;
    }
    __syncthreads();
    float inv = 1.0f / *s_sum;
    if (t < LF_) {
        float a = s_att[t] * inv;
        s_att[t] = a;
        ST<BF>(out, OUT_SELFATT + g * LF_ + t, a);
    }
    __syncthreads();
    float fc = 0.f;
    #pragma unroll 8
    for (int l = 0; l < LF_; ++l)
        fc += us2f(fp[l * D_ + t]) * s_att[l];
    ST<BF>(out, OUT_FRAGCODE + g * D_ + t, fc);
}
__global__ __launch_bounds__(128) void k_fragatt(
    const void* saW, const void* fmask, const float* ws, void* out)
{
    __shared__ float s_att[LF_];
    __shared__ float s_sum;
    if (((const int*)ws)[WS_FLAG]) fragatt_body<true >(saW, fmask, ws, out, s_att, &s_sum);
    else                           fragatt_body<false>(saW, fmask, ws, out, s_att, &s_sum);
}

// ---------------- Kernel 2b: f_att[bwf][l][v] = fp[l,:] @ f_att_W ----------------
// grid = 128 blocks: (bwf, half), 256 thr. Output bf16 into ws.
template<bool BF>
__device__ __forceinline__ void fatt_body(
    const void* fattW, float* ws, u16* sfp /*32x128*/)
{
    int blk = blockIdx.x;
    int bwf = blk >> 1, half = blk & 1;
    int t = threadIdx.x;
    // stage 32 rows of fp (bf16) into LDS: 2048 u32
    const u32* src = (const u32*)((const u16*)(ws + WS_FP16)
                      + (size_t)bwf * (LF_ * D_) + half * 32 * D_);
    u32* dst = (u32*)sfp;
    #pragma unroll
    for (int k = 0; k < 8; ++k) dst[t + 256 * k] = src[t + 256 * k];
    __syncthreads();
    int v = t & 63, lg = t >> 6;        // lg = wave = row group
    float acc[8];
    #pragma unroll
    for (int i = 0; i < 8; ++i) acc[i] = 0.f;
    for (int d = 0; d < D_; d += 2) {
        float w0 = LD<BF>(fattW, d * V_ + v);
        float w1 = LD<BF>(fattW, (d + 1) * V_ + v);
        #pragma unroll
        for (int i = 0; i < 8; ++i) {
            u32 p = *(const u32*)&sfp[(lg * 8 + i) * D_ + d];
            acc[i] += lo2f(p) * w0 + hi2f(p) * w1;
        }
    }
    u16* fa = (u16*)(ws + WS_FATT16) + (size_t)bwf * (LF_ * V_);
    #pragma unroll
    for (int i = 0; i < 8; ++i) {
        int l = half * 32 + lg * 8 + i;
        fa[l * V_ + v] = f2b_raw(acc[i]);
    }
}
__global__ __launch_bounds__(256) void k_fatt(const void* fattW, float* ws)
{
    __shared__ u16 sfp[32 * D_];
    if (((const int*)ws)[WS_FLAG]) fatt_body<true >(fattW, ws, sfp);
    else                           fatt_body<false>(fattW, ws, sfp);
}

// ---------------- Kernel 3: MFMA qf pass ----------------
// block = (bwf, qtile of 16): 512 blocks, 256 thr = 4 waves.
// wave handles l-quarter (16 l). Per l: A = (qp ⊙ fp[l]) [16q x 32k] built in
// regs, B = W3 frags (preloaded), C init = f_att[l,v]; running max over l.
// smem: [0,16384) fp tile u16[64][128]; [16384,32768) f_att f32[64][64];
//       overlay after l-loop: pmax f32[4][16][68] (17408 B).
template<bool BF>
__device__ __forceinline__ void qf_body(
    const void* qfW, const void* gatew, const void* valw, const void* qmask,
    float* ws, void* out, char* smem)
{
    u16*   s_fp   = (u16*)smem;
    float* s_fatt = (float*)(smem + 16384);
    float* s_pmax = (float*)smem;

    int t = threadIdx.x;
    int lane = t & 63, wave = t >> 6;
    int bwf = blockIdx.x >> 3, qt = blockIdx.x & 7;
    int b = bwf >> 4;
    int m = lane & 15, quad = lane >> 4;

    // stage fp tile (4096 u32) and f_att tile (2048 u32 -> 4096 f32)
    {
        const u32* fps = (const u32*)((const u16*)(ws + WS_FP16) + (size_t)bwf * (LF_ * D_));
        u32* d32 = (u32*)s_fp;
        #pragma unroll
        for (int k = 0; k < 16; ++k) d32[t + 256 * k] = fps[t + 256 * k];
        const u32* fas = (const u32*)((const u16*)(ws + WS_FATT16) + (size_t)bwf * (LF_ * V_));
        #pragma unroll
        for (int k = 0; k < 8; ++k) {
            int i = t + 256 * k;
            u32 p = fas[i];
            s_fatt[2 * i]     = lo2f(p);
            s_fatt[2 * i + 1] = hi2f(p);
        }
    }

    // qp fragments: qpreg[kt][j] = qp[q=m][k = kt*32 + quad*8 + j]  (f32)
    float qpreg[4][8];
    {
        const float* qprow = ws + WS_QP + (size_t)(b * LQ_ + qt * 16 + m) * D_;
        #pragma unroll
        for (int kt = 0; kt < 4; ++kt) {
            f32x4 a = *(const f32x4*)(qprow + kt * 32 + quad * 8);
            f32x4 c = *(const f32x4*)(qprow + kt * 32 + quad * 8 + 4);
            qpreg[kt][0]=a.x; qpreg[kt][1]=a.y; qpreg[kt][2]=a.z; qpreg[kt][3]=a.w;
            qpreg[kt][4]=c.x; qpreg[kt][5]=c.y; qpreg[kt][6]=c.z; qpreg[kt][7]=c.w;
        }
    }
    // W3 fragments: w3f[vt][kt], elem j = W3[kt*32+quad*8+j][vt*16+m]
    bf16x8 w3f[4][4];
    #pragma unroll
    for (int vt = 0; vt < 4; ++vt)
        #pragma unroll
        for (int kt = 0; kt < 4; ++kt) {
            short tmp[8];
            #pragma unroll
            for (int j = 0; j < 8; ++j)
                tmp[j] = (short)LDB<BF>(qfW, (kt * 32 + quad * 8 + j) * V_ + vt * 16 + m);
            bf16x8 f;
            #pragma unroll
            for (int j = 0; j < 8; ++j) f[j] = tmp[j];
            w3f[vt][kt] = f;
        }
    __syncthreads();

    float mx[4][4];
    #pragma unroll
    for (int vt = 0; vt < 4; ++vt)
        #pragma unroll
        for (int r = 0; r < 4; ++r) mx[vt][r] = -1e30f;

    int lbase = wave * 16;
    #pragma unroll 2
    for (int li = 0; li < 16; ++li) {
        int l = lbase + li;
        // build A frags: af[kt] = bf16( qp ⊙ fp[l] )
        bf16x8 af[4];
        #pragma unroll
        for (int kt = 0; kt < 4; ++kt) {
            u32x4 fv = *(const u32x4*)&s_fp[l * D_ + kt * 32 + quad * 8];
            u32x4 av;
            av.x = pk2(qpreg[kt][1] * hi2f(fv.x), qpreg[kt][0] * lo2f(fv.x));
            av.y = pk2(qpreg[kt][3] * hi2f(fv.y), qpreg[kt][2] * lo2f(fv.y));
            av.z = pk2(qpreg[kt][5] * hi2f(fv.z), qpreg[kt][4] * lo2f(fv.z));
            av.w = pk2(qpreg[kt][7] * hi2f(fv.w), qpreg[kt][6] * lo2f(fv.w));
            af[kt] = __builtin_bit_cast(bf16x8, av);
        }
        #pragma unroll
        for (int vt = 0; vt < 4; ++vt) {
            float fa = s_fatt[l * V_ + vt * 16 + m];
            f32x4 acc = {fa, fa, fa, fa};
            #pragma unroll
            for (int kt = 0; kt < 4; ++kt)
                acc = __builtin_amdgcn_mfma_f32_16x16x32_bf16(af[kt], w3f[vt][kt], acc, 0, 0, 0);
            #pragma unroll
            for (int r = 0; r < 4; ++r) mx[vt][r] = fmaxf(mx[vt][r], acc[r]);
        }
    }
    __syncthreads();   // all waves done with s_fp/s_fatt
    // pmax[wave][q][v] with padded q-stride 68
    #pragma unroll
    for (int vt = 0; vt < 4; ++vt)
        #pragma unroll
        for (int r = 0; r < 4; ++r)
            s_pmax[wave * 1088 + (quad * 4 + r) * 68 + vt * 16 + m] = mx[vt][r];
    __syncthreads();

    // epilogue: thread -> (q = t>>4, vg = t&15), v = vg*4..vg*4+3
    int q = t >> 4, vg = t & 15;
    int gq = qt * 16 + q;
    float gp = 0.f, ep = 0.f;
    #pragma unroll
    for (int jj = 0; jj < 4; ++jj) {
        int v = vg * 4 + jj;
        float mval = -1e30f;
        #pragma unroll
        for (int w = 0; w < 4; ++w)
            mval = fmaxf(mval, s_pmax[w * 1088 + q * 68 + v]);
        float qf = mval + ws[WS_QATT + (size_t)(b * LQ_ + gq) * V_ + v];
        gp += qf * LD<BF>(gatew, v);
        ep += qf * LD<BF>(valw, v);
    }
    #pragma unroll
    for (int off = 1; off <= 8; off <<= 1) {
        gp += __shfl_xor(gp, off, 64);
        ep += __shfl_xor(ep, off, 64);
    }
    if (vg == 0) {
        float qm = LD<BF>(qmask, b * LQ_ + gq);
        float g = (1.0f / (1.0f + expf(-gp))) * qm;
        ST<BF>(out, OUT_QFGATE + bwf * LQ_ + gq, g);
        ws[WS_E2 + bwf * LQ_ + gq] = expf(ep) * qm;
    }
}
__global__ __launch_bounds__(256) void k_qf(
    const void* qfW, const void* gatew, const void* valw, const void* qmask,
    float* ws, void* out)
{
    __shared__ char smem[32768];
    if (((const int*)ws)[WS_FLAG]) qf_body<true >(qfW, gatew, valw, qmask, ws, out, smem);
    else                           qf_body<false>(qfW, gatew, valw, qmask, ws, out, smem);
}

// ---------------- Kernel 4: e2 softmax over LQ + query_code ----------------
template<bool BF>
__device__ __forceinline__ void qcode_body(const float* ws, void* out,
                                           float* s_n, float* s_sum)
{
    int bwf = blockIdx.x;
    int b = bwf >> 4;
    int t = threadIdx.x;
    float e = ws[WS_E2 + bwf * LQ_ + t];
    s_n[t] = e;
    __syncthreads();
    if (t == 0) {
        float s = 0.f;
        for (int q = 0; q < LQ_; ++q) s += s_n[q];
        *s_sum = s + 1e-7f;
    }
    __syncthreads();
    float inv = 1.0f / *s_sum;
    s_n[t] = e * inv;
    __syncthreads();
    float qc = 0.f;
    #pragma unroll 8
    for (int q = 0; q < LQ_; ++q)
        qc += ws[WS_QP + (size_t)(b * LQ_ + q) * D_ + t] * s_n[q];
    ST<BF>(out, OUT_QUERYCODE + bwf * D_ + t, qc);
}
__global__ __launch_bounds__(128) void k_qcode(const float* ws, void* out)
{
    __shared__ float s_n[LQ_];
    __shared__ float s_sum;
    if (((const int*)ws)[WS_FLAG]) qcode_body<true >(ws, out, s_n, &s_sum);
    else                           qcode_body<false>(ws, out, s_n, &s_sum);
}

extern "C" void kernel_launch(void* const* d_in, const int* in_sizes, int n_in,
                              void* d_out, int out_size, void* d_ws, size_t ws_size,
                              hipStream_t stream)
{
    const void* query    = d_in[0];
    const void* fragment = d_in[1];
    const void* qmask    = d_in[2];
    const void* fmask    = d_in[3];
    const void* projW    = d_in[4];
    const void* projB    = d_in[5];
    const void* saW      = d_in[6];
    const void* qattW    = d_in[7];
    const void* fattW    = d_in[8];
    const void* qfW      = d_in[9];
    const void* gatew    = d_in[10];
    const void* valw     = d_in[11];
    float* ws = (float*)d_ws;

    hipLaunchKernelGGL(k_flag, dim3(1), dim3(1), 0, stream, qmask, ws);
    hipLaunchKernelGGL(k_proj, dim3(NROW_Q + NROW_F), dim3(128), 0, stream,
                       query, fragment, projW, projB, qattW, ws, d_out);
    hipLaunchKernelGGL(k_fragatt, dim3(B_ * NW_ * NFR_), dim3(128), 0, stream,
                       saW, fmask, ws, d_out);
    hipLaunchKernelGGL(k_fatt, dim3(128), dim3(256), 0, stream, fattW, ws);
    hipLaunchKernelGGL(k_qf, dim3(512), dim3(256), 0, stream,
                       qfW, gatew, valw, qmask, ws, d_out);
    hipLaunchKernelGGL(k_qcode, dim3(B_ * NWF_), dim3(128), 0, stream,
                       ws, d_out);
}

// Round 4
// 120.323 us; speedup vs baseline: 2.9106x; 1.1063x over previous
//
#include <hip/hip_runtime.h>
#include <hip/hip_bf16.h>

#define B_   4
#define LQ_  128
#define LF_  64
#define NW_  2
#define NFR_ 8
#define E_   128
#define D_   128
#define V_   64
#define NWF_ (NW_*NFR_)            // 16
#define NROW_Q (B_*LQ_)            // 512
#define NROW_F (B_*NW_*NFR_*LF_)   // 4096

using bf16 = __hip_bfloat16;
typedef unsigned short u16;
typedef unsigned int   u32;
typedef __attribute__((ext_vector_type(8))) short  bf16x8;
typedef __attribute__((ext_vector_type(4))) float  f32x4;
typedef __attribute__((ext_vector_type(4))) u32    u32x4;

// ---- workspace layout (float-index units) ----
// qp    @ 0       [512][128] f32       65536
// qatt  @ 65536   [512][64]  f32       32768
// e2    @ 98304   [64][128]  f32        8192
// fp16  @ 106496  [4096][128] u16     262144 f
// w3t   @ 368640  [64][128] u16 (W3^T)  4096 f
// wft   @ 372736  [64][128] u16 (Wf^T)  4096 f
#define WS_QP    0
#define WS_QATT  65536
#define WS_E2    98304
#define WS_FP16  106496
#define WS_W3T   368640
#define WS_WFT   372736

// ---- out layout (element units; u16 if BF out else f32) ----
#define OUT_FRAGCODE  0       // (B,NW,NFR,D)   8192
#define OUT_QUERYCODE 8192    // (B,NW,NFR,D)   8192
#define OUT_SELFATT   16384   // (B,NW,NFR,LF)  4096
#define OUT_QFGATE    20480   // (B,16,LQ)      8192
#define OUT_QUERY     28672   // (B,LQ,D)       65536

__device__ __forceinline__ float us2f(u16 v) { return __uint_as_float((u32)v << 16); }
__device__ __forceinline__ float lo2f(u32 v) { return __uint_as_float(v << 16); }
__device__ __forceinline__ float hi2f(u32 v) { return __uint_as_float(v & 0xffff0000u); }
__device__ __forceinline__ u16 f2b_raw(float f) {
    u32 u = __float_as_uint(f);
    return (u16)((u + 0x7fffu + ((u >> 16) & 1u)) >> 16);
}
// truncating pack (1 v_perm) — used only for A-fragment products
__device__ __forceinline__ u32 pk2(float hi, float lo) {
    return __builtin_amdgcn_perm(__float_as_uint(hi), __float_as_uint(lo), 0x07060302u);
}
template<bool BF> __device__ __forceinline__ float LD(const void* p, int i) {
    return BF ? us2f(((const u16*)p)[i]) : ((const float*)p)[i];
}
template<bool BF> __device__ __forceinline__ void ST(void* p, int i, float v) {
    if (BF) ((u16*)p)[i] = f2b_raw(v); else ((float*)p)[i] = v;
}
template<bool BF> __device__ __forceinline__ u16 LDB(const void* p, int i) {
    return BF ? ((const u16*)p)[i] : f2b_raw(((const float*)p)[i]);
}
__device__ __forceinline__ bool is_bf(const void* qmask) {
    return ((const u16*)qmask)[0] == 0x3F80u;
}

// ================= K1: MFMA projection + q_att + weight transposes =========
// blocks 0..71: 64 rows each of [query(512); fragment(4096)] @ projW + b.
//   blocks 0..7 are query blocks: also compute q_att = Y @ qattW.
// blocks 72,73: transpose-convert qfW / fattW -> bf16 [v][k] in ws.
template<bool BF>
__device__ __forceinline__ void proj_body(
    const void* query, const void* fragment, const void* projW, const void* projB,
    const void* qattW, const void* qfW, const void* fattW,
    float* ws, void* out, char* smem)
{
    int bx = blockIdx.x, t = threadIdx.x;
    if (bx >= 72) {
        // ---- transpose-convert a 128x64 weight into u16 [v][k] ----
        const void* src = (bx == 72) ? qfW : fattW;
        u16* dst = (u16*)(ws + ((bx == 72) ? WS_W3T : WS_WFT));
        u16* stg = (u16*)smem;                 // [128][65] u16
        #pragma unroll
        for (int it = 0; it < 32; ++it) {
            int i = t + 256 * it;              // 8192 elements [k][v]
            int k = i >> 6, v = i & 63;
            stg[k * 65 + v] = LDB<BF>(src, i);
        }
        __syncthreads();
        #pragma unroll
        for (int it = 0; it < 32; ++it) {
            int j = t + 256 * it;              // [v][k] order out
            int vo = j >> 7, ko = j & 127;
            dst[vo * 128 + ko] = stg[ko * 65 + vo];
        }
        return;
    }
    u16*   s_x  = (u16*)smem;                  // [64][128] swizzled bf16
    u16*   s_wt = (u16*)(smem + 16384);        // [128][128] swizzled bf16 (W^T)
    u16*   s_y  = (u16*)(smem + 32768);        // [64][128] swizzled (query blocks)
    float* s_b  = (float*)(smem + 49152);      // [128]
    bool isq = (bx < 8);
    int r0 = bx * 64;
    int rowbase = isq ? r0 : (r0 - NROW_Q);
    const void* xsrc = isq ? query : fragment;

    // stage X tile (bf16, row-swizzled)
    #pragma unroll
    for (int it = 0; it < 16; ++it) {
        int i = t + 256 * it;                  // u32-pair index, 4096 total
        int row = i >> 6, cp = i & 63;
        u32 val;
        if (BF) val = ((const u32*)xsrc)[(size_t)(rowbase + row) * 64 + cp];
        else {
            float2 f = ((const float2*)xsrc)[(size_t)(rowbase + row) * 64 + cp];
            val = ((u32)f2b_raw(f.y) << 16) | f2b_raw(f.x);
        }
        ((u32*)s_x)[row * 64 + (cp ^ ((row & 7) << 2))] = val;
    }
    // stage W^T (projW [k][n] -> s_wt[n][k], swizzled)
    #pragma unroll
    for (int it = 0; it < 32; ++it) {
        int i = t + 256 * it;                  // pair index, 8192 total
        int k = i >> 6, np = (i & 63) * 2;
        u16 lo, hi;
        if (BF) { u32 v2 = ((const u32*)projW)[i]; lo = (u16)(v2 & 0xffffu); hi = (u16)(v2 >> 16); }
        else { float2 f = ((const float2*)projW)[i]; lo = f2b_raw(f.x); hi = f2b_raw(f.y); }
        s_wt[(np)     * 128 + (k ^ (((np)     & 7) << 3))] = lo;
        s_wt[(np + 1) * 128 + (k ^ (((np + 1) & 7) << 3))] = hi;
    }
    if (t < 128) s_b[t] = LD<BF>(projB, t);
    __syncthreads();

    int lane = t & 63, wave = t >> 6, m = lane & 15, quad = lane >> 4;
    f32x4 acc[8];
    #pragma unroll
    for (int nt = 0; nt < 8; ++nt) { float bv = s_b[nt * 16 + m]; acc[nt] = (f32x4){bv, bv, bv, bv}; }
    int arow = wave * 16 + m;
    int sk = (m & 7) << 3;
    #pragma unroll
    for (int kt = 0; kt < 4; ++kt) {
        int kx = (kt * 32 + quad * 8) ^ sk;
        bf16x8 a = *(const bf16x8*)&s_x[arow * 128 + kx];
        #pragma unroll
        for (int nt = 0; nt < 8; ++nt) {
            bf16x8 b = *(const bf16x8*)&s_wt[(nt * 16 + m) * 128 + kx];
            acc[nt] = __builtin_amdgcn_mfma_f32_16x16x32_bf16(a, b, acc[nt], 0, 0, 0);
        }
    }
    int growbase = r0 + wave * 16 + quad * 4;
    if (!isq) {
        u16* fp16 = (u16*)(ws + WS_FP16);
        #pragma unroll
        for (int nt = 0; nt < 8; ++nt)
            #pragma unroll
            for (int rr = 0; rr < 4; ++rr)
                fp16[(size_t)(growbase + rr - NROW_Q) * 128 + nt * 16 + m] = f2b_raw(acc[nt][rr]);
    } else {
        // global stores first (no LDS hazard), then barrier, then LDS reuse
        #pragma unroll
        for (int nt = 0; nt < 8; ++nt)
            #pragma unroll
            for (int rr = 0; rr < 4; ++rr) {
                float v = acc[nt][rr];
                int gr = growbase + rr, col = nt * 16 + m;
                ws[WS_QP + (size_t)gr * 128 + col] = v;
                ST<BF>(out, OUT_QUERY + gr * 128 + col, v);
            }
        __syncthreads();   // everyone done reading s_wt/s_x
        // write Y (bf16) into s_y, stage qattW^T into s_wt rows 0..63
        #pragma unroll
        for (int nt = 0; nt < 8; ++nt)
            #pragma unroll
            for (int rr = 0; rr < 4; ++rr) {
                int lr = wave * 16 + quad * 4 + rr, col = nt * 16 + m;
                s_y[lr * 128 + (col ^ ((lr & 7) << 3))] = f2b_raw(acc[nt][rr]);
            }
        #pragma unroll
        for (int it = 0; it < 16; ++it) {
            int i = t + 256 * it;              // pair index, 4096 (qattW 128x64)
            int k = i >> 5, np = (i & 31) * 2;
            u16 lo, hi;
            if (BF) { u32 v2 = ((const u32*)qattW)[i]; lo = (u16)(v2 & 0xffffu); hi = (u16)(v2 >> 16); }
            else { float2 f = ((const float2*)qattW)[i]; lo = f2b_raw(f.x); hi = f2b_raw(f.y); }
            s_wt[(np)     * 128 + (k ^ (((np)     & 7) << 3))] = lo;
            s_wt[(np + 1) * 128 + (k ^ (((np + 1) & 7) << 3))] = hi;
        }
        __syncthreads();
        f32x4 acc2[4];
        #pragma unroll
        for (int nt = 0; nt < 4; ++nt) acc2[nt] = (f32x4){0.f, 0.f, 0.f, 0.f};
        #pragma unroll
        for (int kt = 0; kt < 4; ++kt) {
            int kx = (kt * 32 + quad * 8) ^ sk;
            bf16x8 a = *(const bf16x8*)&s_y[(wave * 16 + m) * 128 + kx];
            #pragma unroll
            for (int nt = 0; nt < 4; ++nt) {
                bf16x8 b = *(const bf16x8*)&s_wt[(nt * 16 + m) * 128 + kx];
                acc2[nt] = __builtin_amdgcn_mfma_f32_16x16x32_bf16(a, b, acc2[nt], 0, 0, 0);
            }
        }
        #pragma unroll
        for (int nt = 0; nt < 4; ++nt)
            #pragma unroll
            for (int rr = 0; rr < 4; ++rr)
                ws[WS_QATT + (size_t)(growbase + rr) * 64 + nt * 16 + m] = acc2[nt][rr];
    }
}
__global__ __launch_bounds__(256) void k_proj(
    const void* query, const void* fragment, const void* projW, const void* projB,
    const void* qattW, const void* qfW, const void* fattW, const void* qmask,
    float* ws, void* out)
{
    __shared__ char smem[49664];
    if (is_bf(qmask)) proj_body<true >(query, fragment, projW, projB, qattW, qfW, fattW, ws, out, smem);
    else              proj_body<false>(query, fragment, projW, projB, qattW, qfW, fattW, ws, out, smem);
}

// ================= K2: MFMA qf pass + fused f_att + fused fragatt ==========
// block = (bwf, qtile): 512 blocks, 256 thr = 4 waves; wave owns 16 l's.
template<bool BF>
__device__ __forceinline__ void qf_body(
    const void* saW, const void* fmask, const void* gatew, const void* valw,
    const void* qmask, float* ws, void* out, char* smem)
{
    u16*   s_fp   = (u16*)smem;                 // [64][128] swizzled bf16
    float* s_fatt = (float*)(smem + 16384);     // [64][68]; pmax overlay [4][16][68]
    float* s_pmax = s_fatt;
    float* s_saw  = (float*)(smem + 33792);     // [128]
    float* s_att  = (float*)(smem + 34304);     // [64]
    float* s_tmp  = (float*)(smem + 34560);     // [128]

    int t = threadIdx.x, lane = t & 63, wave = t >> 6;
    int bwf = blockIdx.x >> 3, qt = blockIdx.x & 7;
    int b = bwf >> 4;
    int m = lane & 15, quad = lane >> 4;
    int sk = (m & 7) << 3;

    // stage fp tile (swizzled rows)
    {
        const u32* src = (const u32*)((const u16*)(ws + WS_FP16)) + (size_t)bwf * 4096;
        u32* d32 = (u32*)s_fp;
        #pragma unroll
        for (int k = 0; k < 16; ++k) {
            int i = t + 256 * k;
            int row = i >> 6, cp = i & 63;
            d32[row * 64 + (cp ^ ((row & 7) << 2))] = src[i];
        }
    }
    // B-fragments for W3 / Wf from pre-transposed bf16 copies (b128 loads)
    const u16* w3t = (const u16*)(ws + WS_W3T);
    const u16* wft = (const u16*)(ws + WS_WFT);
    bf16x8 w3f[4][4], wff[4][4];
    #pragma unroll
    for (int vt = 0; vt < 4; ++vt)
        #pragma unroll
        for (int kt = 0; kt < 4; ++kt) {
            int off = (vt * 16 + m) * 128 + kt * 32 + quad * 8;
            w3f[vt][kt] = *(const bf16x8*)(w3t + off);
            wff[vt][kt] = *(const bf16x8*)(wft + off);
        }
    __syncthreads();

    int lbase = wave * 16;
    // f_att tile via MFMA: rows lbase..lbase+15 (wave-private in s_fatt)
    {
        bf16x8 afk[4];
        #pragma unroll
        for (int kt = 0; kt < 4; ++kt) {
            int kx = (kt * 32 + quad * 8) ^ sk;
            afk[kt] = *(const bf16x8*)&s_fp[(lbase + m) * 128 + kx];
        }
        #pragma unroll
        for (int vt = 0; vt < 4; ++vt) {
            f32x4 a0 = (f32x4){0.f, 0.f, 0.f, 0.f};
            #pragma unroll
            for (int kt = 0; kt < 4; ++kt)
                a0 = __builtin_amdgcn_mfma_f32_16x16x32_bf16(afk[kt], wff[vt][kt], a0, 0, 0, 0);
            #pragma unroll
            for (int r = 0; r < 4; ++r)
                s_fatt[(lbase + quad * 4 + r) * 68 + vt * 16 + m] = a0[r];
        }
    }
    // qp fragments (f32)
    float qpreg[4][8];
    {
        const float* qprow = ws + WS_QP + (size_t)(b * LQ_ + qt * 16 + m) * 128;
        #pragma unroll
        for (int kt = 0; kt < 4; ++kt) {
            f32x4 x0 = *(const f32x4*)(qprow + kt * 32 + quad * 8);
            f32x4 x1 = *(const f32x4*)(qprow + kt * 32 + quad * 8 + 4);
            qpreg[kt][0] = x0.x; qpreg[kt][1] = x0.y; qpreg[kt][2] = x0.z; qpreg[kt][3] = x0.w;
            qpreg[kt][4] = x1.x; qpreg[kt][5] = x1.y; qpreg[kt][6] = x1.z; qpreg[kt][7] = x1.w;
        }
    }

    float mx[4][4];
    #pragma unroll
    for (int vt = 0; vt < 4; ++vt)
        #pragma unroll
        for (int r = 0; r < 4; ++r) mx[vt][r] = -1e30f;

    #pragma unroll 2
    for (int li = 0; li < 16; ++li) {
        int l = lbase + li;
        bf16x8 af[4];
        #pragma unroll
        for (int kt = 0; kt < 4; ++kt) {
            const u16* p = &s_fp[l * 128 + ((kt * 32 + quad * 8) ^ ((li & 7) << 3))];
            u32x4 fv = *(const u32x4*)p;
            u32x4 av;
            av.x = pk2(qpreg[kt][1] * hi2f(fv.x), qpreg[kt][0] * lo2f(fv.x));
            av.y = pk2(qpreg[kt][3] * hi2f(fv.y), qpreg[kt][2] * lo2f(fv.y));
            av.z = pk2(qpreg[kt][5] * hi2f(fv.z), qpreg[kt][4] * lo2f(fv.z));
            av.w = pk2(qpreg[kt][7] * hi2f(fv.w), qpreg[kt][6] * lo2f(fv.w));
            af[kt] = __builtin_bit_cast(bf16x8, av);
        }
        #pragma unroll
        for (int vt = 0; vt < 4; ++vt) {
            float fa = s_fatt[l * 68 + vt * 16 + m];
            f32x4 acc = (f32x4){fa, fa, fa, fa};
            #pragma unroll
            for (int kt = 0; kt < 4; ++kt)
                acc = __builtin_amdgcn_mfma_f32_16x16x32_bf16(af[kt], w3f[vt][kt], acc, 0, 0, 0);
            #pragma unroll
            for (int r = 0; r < 4; ++r) mx[vt][r] = fmaxf(mx[vt][r], acc[r]);
        }
    }
    // pmax[wave] overlays exactly this wave's own s_fatt rows — no pre-sync needed
    #pragma unroll
    for (int vt = 0; vt < 4; ++vt)
        #pragma unroll
        for (int r = 0; r < 4; ++r)
            s_pmax[wave * 1088 + (quad * 4 + r) * 68 + vt * 16 + m] = mx[vt][r];
    __syncthreads();

    // epilogue: thread -> (q = t>>4, vg = t&15)
    {
        int q = t >> 4, vg = t & 15;
        int gq = qt * 16 + q;
        float gp = 0.f, ep = 0.f;
        #pragma unroll
        for (int jj = 0; jj < 4; ++jj) {
            int v = vg * 4 + jj;
            float mval = -1e30f;
            #pragma unroll
            for (int w = 0; w < 4; ++w)
                mval = fmaxf(mval, s_pmax[w * 1088 + q * 68 + v]);
            float qf = mval + ws[WS_QATT + (size_t)(b * LQ_ + gq) * 64 + v];
            gp += qf * LD<BF>(gatew, v);
            ep += qf * LD<BF>(valw, v);
        }
        #pragma unroll
        for (int off = 1; off <= 8; off <<= 1) {
            gp += __shfl_xor(gp, off, 64);
            ep += __shfl_xor(ep, off, 64);
        }
        if (vg == 0) {
            float qm = LD<BF>(qmask, b * LQ_ + gq);
            float g = (1.0f / (1.0f + expf(-gp))) * qm;
            ST<BF>(out, OUT_QFGATE + bwf * LQ_ + gq, g);
            ws[WS_E2 + bwf * LQ_ + gq] = expf(ep) * qm;
        }
    }

    // fused fragment self-attention (qt==0 blocks only; block-uniform branch)
    if (qt == 0) {
        if (t < 128) s_saw[t] = LD<BF>(saW, ((bwf >> 3) & 1) * 128 + t);
        __syncthreads();
        int l = t >> 2, j4 = t & 3;
        float p = 0.f;
        #pragma unroll
        for (int it = 0; it < 4; ++it) {
            int koff = j4 * 32 + it * 8;
            const u16* pp = &s_fp[l * 128 + (koff ^ ((l & 7) << 3))];
            u32x4 fv = *(const u32x4*)pp;
            const float* swp = &s_saw[koff];
            p += lo2f(fv.x) * swp[0] + hi2f(fv.x) * swp[1]
               + lo2f(fv.y) * swp[2] + hi2f(fv.y) * swp[3]
               + lo2f(fv.z) * swp[4] + hi2f(fv.z) * swp[5]
               + lo2f(fv.w) * swp[6] + hi2f(fv.w) * swp[7];
        }
        p += __shfl_xor(p, 1, 64);
        p += __shfl_xor(p, 2, 64);
        if (j4 == 0) s_att[l] = expf(p) * LD<BF>(fmask, bwf * LF_ + l);
        __syncthreads();
        if (t < 64) {
            float e = s_att[t], s = e;
            #pragma unroll
            for (int off = 1; off <= 32; off <<= 1) s += __shfl_xor(s, off, 64);
            float nrm = e / (s + 1e-7f);
            s_att[t] = nrm;
            ST<BF>(out, OUT_SELFATT + bwf * LF_ + t, nrm);
        }
        __syncthreads();
        int d = t & 127, half = t >> 7;
        float fc = 0.f;
        #pragma unroll
        for (int li2 = 0; li2 < 32; ++li2) {
            int l2 = half * 32 + li2;
            fc += us2f(s_fp[l2 * 128 + (d ^ ((l2 & 7) << 3))]) * s_att[l2];
        }
        if (half == 1) s_tmp[d] = fc;
        __syncthreads();
        if (half == 0) ST<BF>(out, OUT_FRAGCODE + bwf * D_ + d, fc + s_tmp[d]);
    }
}
__global__ __launch_bounds__(256) void k_qf(
    const void* saW, const void* fmask, const void* gatew, const void* valw,
    const void* qmask, float* ws, void* out)
{
    __shared__ char smem[35072];
    if (is_bf(qmask)) qf_body<true >(saW, fmask, gatew, valw, qmask, ws, out, smem);
    else              qf_body<false>(saW, fmask, gatew, valw, qmask, ws, out, smem);
}

// ================= K3: e2 softmax over LQ + query_code =====================
template<bool BF>
__device__ __forceinline__ void qcode_body(const float* ws, void* out,
                                           float* s_n, float* s_part)
{
    int bwf = blockIdx.x, b = bwf >> 4, t = threadIdx.x;
    float e = ws[WS_E2 + bwf * LQ_ + t];
    float s = e;
    #pragma unroll
    for (int off = 1; off <= 32; off <<= 1) s += __shfl_xor(s, off, 64);
    if ((t & 63) == 0) s_part[t >> 6] = s;
    __syncthreads();
    float tot = s_part[0] + s_part[1] + 1e-7f;
    s_n[t] = e / tot;
    __syncthreads();
    float qc = 0.f;
    #pragma unroll 8
    for (int q = 0; q < LQ_; ++q)
        qc += ws[WS_QP + (size_t)(b * LQ_ + q) * 128 + t] * s_n[q];
    ST<BF>(out, OUT_QUERYCODE + bwf * D_ + t, qc);
}
__global__ __launch_bounds__(128) void k_qcode(const void* qmask, const float* ws, void* out)
{
    __shared__ float s_n[LQ_];
    __shared__ float s_part[2];
    if (is_bf(qmask)) qcode_body<true >(ws, out, s_n, s_part);
    else              qcode_body<false>(ws, out, s_n, s_part);
}

extern "C" void kernel_launch(void* const* d_in, const int* in_sizes, int n_in,
                              void* d_out, int out_size, void* d_ws, size_t ws_size,
                              hipStream_t stream)
{
    const void* query    = d_in[0];
    const void* fragment = d_in[1];
    const void* qmask    = d_in[2];
    const void* fmask    = d_in[3];
    const void* projW    = d_in[4];
    const void* projB    = d_in[5];
    const void* saW      = d_in[6];
    const void* qattW    = d_in[7];
    const void* fattW    = d_in[8];
    const void* qfW      = d_in[9];
    const void* gatew    = d_in[10];
    const void* valw     = d_in[11];
    float* ws = (float*)d_ws;

    hipLaunchKernelGGL(k_proj, dim3(74), dim3(256), 0, stream,
                       query, fragment, projW, projB, qattW, qfW, fattW, qmask, ws, d_out);
    hipLaunchKernelGGL(k_qf, dim3(512), dim3(256), 0, stream,
                       saW, fmask, gatew, valw, qmask, ws, d_out);
    hipLaunchKernelGGL(k_qcode, dim3(B_ * NWF_), dim3(128), 0, stream,
                       qmask, ws, d_out);
}

// Round 5
// 114.242 us; speedup vs baseline: 3.0656x; 1.0532x over previous
//
#include <hip/hip_runtime.h>
#include <hip/hip_bf16.h>

#define B_   4
#define LQ_  128
#define LF_  64
#define NW_  2
#define NFR_ 8
#define E_   128
#define D_   128
#define V_   64
#define NWF_ (NW_*NFR_)            // 16
#define NROW_Q (B_*LQ_)            // 512
#define NROW_F (B_*NW_*NFR_*LF_)   // 4096

using bf16 = __hip_bfloat16;
typedef unsigned short u16;
typedef unsigned int   u32;
typedef __attribute__((ext_vector_type(8))) short  bf16x8;
typedef __attribute__((ext_vector_type(4))) float  f32x4;
typedef __attribute__((ext_vector_type(4))) u32    u32x4;

// ---- workspace layout (float-index units) ----
#define WS_QP    0          // [512][128] f32   65536
#define WS_QATT  65536      // [512][64]  f32   32768
#define WS_E2    98304      // [64][128]  f32    8192
#define WS_FP16  106496     // [4096][128] u16 262144 f
#define WS_W3T   368640     // [64][128]  u16    4096 f
#define WS_WFT   372736     // [64][128]  u16    4096 f
#define WS_PWT   376832     // [128][128] u16    8192 f
#define WS_QAT   385024     // [64][128]  u16    4096 f

// ---- out layout (element units; u16 if BF out else f32) ----
#define OUT_FRAGCODE  0       // (B,NW,NFR,D)   8192
#define OUT_QUERYCODE 8192    // (B,NW,NFR,D)   8192
#define OUT_SELFATT   16384   // (B,NW,NFR,LF)  4096
#define OUT_QFGATE    20480   // (B,16,LQ)      8192
#define OUT_QUERY     28672   // (B,LQ,D)       65536

__device__ __forceinline__ float us2f(u16 v) { return __uint_as_float((u32)v << 16); }
__device__ __forceinline__ float lo2f(u32 v) { return __uint_as_float(v << 16); }
__device__ __forceinline__ float hi2f(u32 v) { return __uint_as_float(v & 0xffff0000u); }
__device__ __forceinline__ u16 f2b_raw(float f) {
    u32 u = __float_as_uint(f);
    return (u16)((u + 0x7fffu + ((u >> 16) & 1u)) >> 16);
}
// truncating pack of two f32 bf16s into one u32 (1 v_perm)
__device__ __forceinline__ u32 pk2(float hi, float lo) {
    return __builtin_amdgcn_perm(__float_as_uint(hi), __float_as_uint(lo), 0x07060302u);
}
template<bool BF> __device__ __forceinline__ float LD(const void* p, int i) {
    return BF ? us2f(((const u16*)p)[i]) : ((const float*)p)[i];
}
template<bool BF> __device__ __forceinline__ void ST(void* p, int i, float v) {
    if (BF) ((u16*)p)[i] = f2b_raw(v); else ((float*)p)[i] = v;
}
template<bool BF> __device__ __forceinline__ u16 LDB(const void* p, int i) {
    return BF ? ((const u16*)p)[i] : f2b_raw(((const float*)p)[i]);
}
__device__ __forceinline__ bool is_bf(const void* qmask) {
    return ((const u16*)qmask)[0] == 0x3F80u;
}

// ================= K_prep: transpose-convert 4 weight matrices =============
// block 0: projW 128x128 -> pwt[n][k]; 1: qattW->qat; 2: qfW->w3t; 3: fattW->wft
template<bool BF>
__device__ __forceinline__ void prep_body(const void* src, u16* dst, u16* stg, int N)
{
    int t = threadIdx.x;
    int st = N + 1, total = 128 * N;
    for (int i = t; i < total; i += 256)
        stg[(i / N) * st + (i % N)] = LDB<BF>(src, i);
    __syncthreads();
    for (int j = t; j < total; j += 256) {
        int n = j >> 7, k = j & 127;
        dst[n * 128 + k] = stg[k * st + n];
    }
}
__global__ __launch_bounds__(256) void k_prep(
    const void* projW, const void* qattW, const void* qfW, const void* fattW,
    const void* qmask, float* ws)
{
    __shared__ u16 stg[128 * 129];
    int bx = blockIdx.x;
    const void* src = (bx == 0) ? projW : (bx == 1) ? qattW : (bx == 2) ? qfW : fattW;
    u16* dst = (u16*)(ws + ((bx == 0) ? WS_PWT : (bx == 1) ? WS_QAT : (bx == 2) ? WS_W3T : WS_WFT));
    int N = (bx == 0) ? 128 : 64;
    if (is_bf(qmask)) prep_body<true >(src, dst, stg, N);
    else              prep_body<false>(src, dst, stg, N);
}

// ================= K_proj: 288 light blocks, zero-LDS GEMM =================
// blocks 0..255: fragment rows [r*16, r*16+16); blocks 256..287: query rows.
// A-frags direct global (k-contiguous rows), B-frags direct from pwt (L2).
template<bool BF>
__device__ __forceinline__ void proj_body(
    const void* query, const void* fragment, const void* projB,
    float* ws, void* out, u16* s_y)
{
    int r = blockIdx.x, t = threadIdx.x;
    int lane = t & 63, wave = t >> 6, m = lane & 15, quad = lane >> 4;
    bool isq = (r >= 256);
    int base = isq ? (r - 256) * 16 : r * 16;
    const void* x = isq ? query : fragment;
    const u16* pwt = (const u16*)(ws + WS_PWT);

    bf16x8 af[4];
    #pragma unroll
    for (int kt = 0; kt < 4; ++kt) {
        int off = (base + m) * 128 + kt * 32 + quad * 8;
        if (BF) af[kt] = *(const bf16x8*)((const u16*)x + off);
        else {
            f32x4 a = *(const f32x4*)((const float*)x + off);
            f32x4 c = *(const f32x4*)((const float*)x + off + 4);
            u32x4 av;
            av.x = pk2(a.y, a.x); av.y = pk2(a.w, a.z);
            av.z = pk2(c.y, c.x); av.w = pk2(c.w, c.z);
            af[kt] = __builtin_bit_cast(bf16x8, av);
        }
    }
    int nt0 = wave * 2;
    f32x4 acc[2];
    #pragma unroll
    for (int i = 0; i < 2; ++i) {
        float bv = LD<BF>(projB, (nt0 + i) * 16 + m);
        acc[i] = (f32x4){bv, bv, bv, bv};
    }
    #pragma unroll
    for (int kt = 0; kt < 4; ++kt)
        #pragma unroll
        for (int i = 0; i < 2; ++i) {
            bf16x8 bfr = *(const bf16x8*)(pwt + ((nt0 + i) * 16 + m) * 128 + kt * 32 + quad * 8);
            acc[i] = __builtin_amdgcn_mfma_f32_16x16x32_bf16(af[kt], bfr, acc[i], 0, 0, 0);
        }
    if (!isq) {
        u16* fp16 = (u16*)(ws + WS_FP16);
        #pragma unroll
        for (int i = 0; i < 2; ++i)
            #pragma unroll
            for (int rr = 0; rr < 4; ++rr)
                fp16[(size_t)(base + quad * 4 + rr) * 128 + (nt0 + i) * 16 + m] = f2b_raw(acc[i][rr]);
    } else {
        #pragma unroll
        for (int i = 0; i < 2; ++i)
            #pragma unroll
            for (int rr = 0; rr < 4; ++rr) {
                int gr = base + quad * 4 + rr, col = (nt0 + i) * 16 + m;
                float v = acc[i][rr];
                ws[WS_QP + (size_t)gr * 128 + col] = v;
                ST<BF>(out, OUT_QUERY + gr * 128 + col, v);
                s_y[(quad * 4 + rr) * 132 + col] = f2b_raw(v);
            }
        __syncthreads();
        // q_att = Y @ qattW  (A from LDS, B from qat)
        bf16x8 ay[4];
        #pragma unroll
        for (int kt = 0; kt < 4; ++kt)
            ay[kt] = *(const bf16x8*)&s_y[m * 132 + kt * 32 + quad * 8];
        const u16* qat = (const u16*)(ws + WS_QAT);
        f32x4 a2 = (f32x4){0.f, 0.f, 0.f, 0.f};
        #pragma unroll
        for (int kt = 0; kt < 4; ++kt) {
            bf16x8 b2 = *(const bf16x8*)(qat + (wave * 16 + m) * 128 + kt * 32 + quad * 8);
            a2 = __builtin_amdgcn_mfma_f32_16x16x32_bf16(ay[kt], b2, a2, 0, 0, 0);
        }
        #pragma unroll
        for (int rr = 0; rr < 4; ++rr)
            ws[WS_QATT + (size_t)(base + quad * 4 + rr) * 64 + wave * 16 + m] = a2[rr];
    }
}
__global__ __launch_bounds__(256) void k_proj(
    const void* query, const void* fragment, const void* projB, const void* qmask,
    float* ws, void* out)
{
    __shared__ u16 s_y[16 * 132];
    if (is_bf(qmask)) proj_body<true >(query, fragment, projB, ws, out, s_y);
    else              proj_body<false>(query, fragment, projB, ws, out, s_y);
}

// ================= K_qf: 256 blocks x 512 thr ==============================
// block = (bwf, qt2 of 32 q); 8 waves: wave = (lq = w>>1, qsub = w&1).
// smem: s_fp u16[64][128] (16384) + fa/pmax u16[128][72] (18432)
//       + saw(512) + att(256) + tmp(2048) = 37632 B
template<bool BF>
__device__ __forceinline__ void qf_body(
    const void* saW, const void* fmask, const void* gatew, const void* valw,
    const void* qmask, float* ws, void* out, char* smem)
{
    u16*   s_fp  = (u16*)smem;                  // [64][128] swizzled
    u16*   s_fa  = (u16*)(smem + 16384);        // fatt rows 0..63 / pmax rows 0..127, stride 72
    float* s_saw = (float*)(smem + 34816);      // [128]
    float* s_att = (float*)(smem + 35328);      // [64]
    float* s_tmp = (float*)(smem + 35584);      // [4][128]

    int t = threadIdx.x, lane = t & 63, wave = t >> 6;
    int bwf = blockIdx.x >> 2, qt2 = blockIdx.x & 3;
    int b = bwf >> 4;
    int m = lane & 15, quad = lane >> 4;
    int lq = wave >> 1, qsub = wave & 1;
    int sk = (m & 7) << 3;

    // stage fp tile (8192 u32, swizzled rows)
    {
        const u32* src = (const u32*)((const u16*)(ws + WS_FP16)) + (size_t)bwf * 4096;
        u32* d32 = (u32*)s_fp;
        #pragma unroll
        for (int k = 0; k < 16; ++k) {
            int i = t + 512 * k;
            int row = i >> 6, cp = i & 63;
            d32[row * 64 + (cp ^ ((row & 7) << 2))] = src[i];
        }
    }
    // W3 B-frags (global, L2-resident)
    const u16* w3t = (const u16*)(ws + WS_W3T);
    bf16x8 w3f[4][4];
    #pragma unroll
    for (int vt = 0; vt < 4; ++vt)
        #pragma unroll
        for (int kt = 0; kt < 4; ++kt)
            w3f[vt][kt] = *(const bf16x8*)(w3t + (vt * 16 + m) * 128 + kt * 32 + quad * 8);
    __syncthreads();

    int lbase = lq * 16;
    // f_att for this l-quarter (even waves only), bf16 into s_fa
    if (qsub == 0) {
        const u16* wft = (const u16*)(ws + WS_WFT);
        bf16x8 afk[4];
        #pragma unroll
        for (int kt = 0; kt < 4; ++kt)
            afk[kt] = *(const bf16x8*)&s_fp[(lbase + m) * 128 + ((kt * 32 + quad * 8) ^ sk)];
        #pragma unroll
        for (int vt = 0; vt < 4; ++vt) {
            bf16x8 wf = *(const bf16x8*)(wft + (vt * 16 + m) * 128 + 0 * 32 + quad * 8);
            f32x4 a0 = (f32x4){0.f, 0.f, 0.f, 0.f};
            #pragma unroll
            for (int kt = 0; kt < 4; ++kt) {
                bf16x8 wk = *(const bf16x8*)(wft + (vt * 16 + m) * 128 + kt * 32 + quad * 8);
                a0 = __builtin_amdgcn_mfma_f32_16x16x32_bf16(afk[kt], wk, a0, 0, 0, 0);
                (void)wf;
            }
            #pragma unroll
            for (int r = 0; r < 4; ++r)
                s_fa[(lbase + quad * 4 + r) * 72 + vt * 16 + m] = f2b_raw(a0[r]);
        }
    }
    // qp fragments (f32)
    float qpreg[4][8];
    {
        const float* qprow = ws + WS_QP + (size_t)(b * LQ_ + qt2 * 32 + qsub * 16 + m) * 128;
        #pragma unroll
        for (int kt = 0; kt < 4; ++kt) {
            f32x4 x0 = *(const f32x4*)(qprow + kt * 32 + quad * 8);
            f32x4 x1 = *(const f32x4*)(qprow + kt * 32 + quad * 8 + 4);
            qpreg[kt][0] = x0.x; qpreg[kt][1] = x0.y; qpreg[kt][2] = x0.z; qpreg[kt][3] = x0.w;
            qpreg[kt][4] = x1.x; qpreg[kt][5] = x1.y; qpreg[kt][6] = x1.z; qpreg[kt][7] = x1.w;
        }
    }
    __syncthreads();   // fatt visible to both waves of the pair

    float mx[4][4];
    #pragma unroll
    for (int vt = 0; vt < 4; ++vt)
        #pragma unroll
        for (int r = 0; r < 4; ++r) mx[vt][r] = -1e30f;

    // software-pipelined l-loop
    u32x4 fvc[4], fvn[4];
    #pragma unroll
    for (int kt = 0; kt < 4; ++kt)
        fvc[kt] = *(const u32x4*)&s_fp[lbase * 128 + (kt * 32 + quad * 8)];
    #pragma unroll 2
    for (int li = 0; li < 16; ++li) {
        if (li < 15) {
            int l2 = lbase + li + 1;
            #pragma unroll
            for (int kt = 0; kt < 4; ++kt)
                fvn[kt] = *(const u32x4*)&s_fp[l2 * 128 + ((kt * 32 + quad * 8) ^ (((li + 1) & 7) << 3))];
        }
        int l = lbase + li;
        bf16x8 af[4];
        #pragma unroll
        for (int kt = 0; kt < 4; ++kt) {
            u32x4 fv = fvc[kt];
            u32x4 av;
            av.x = pk2(qpreg[kt][1] * hi2f(fv.x), qpreg[kt][0] * lo2f(fv.x));
            av.y = pk2(qpreg[kt][3] * hi2f(fv.y), qpreg[kt][2] * lo2f(fv.y));
            av.z = pk2(qpreg[kt][5] * hi2f(fv.z), qpreg[kt][4] * lo2f(fv.z));
            av.w = pk2(qpreg[kt][7] * hi2f(fv.w), qpreg[kt][6] * lo2f(fv.w));
            af[kt] = __builtin_bit_cast(bf16x8, av);
        }
        #pragma unroll
        for (int vt = 0; vt < 4; ++vt) {
            float fa = us2f(s_fa[l * 72 + vt * 16 + m]);
            f32x4 acc = (f32x4){fa, fa, fa, fa};
            #pragma unroll
            for (int kt = 0; kt < 4; ++kt)
                acc = __builtin_amdgcn_mfma_f32_16x16x32_bf16(af[kt], w3f[vt][kt], acc, 0, 0, 0);
            #pragma unroll
            for (int r = 0; r < 4; ++r) mx[vt][r] = fmaxf(mx[vt][r], acc[r]);
        }
        #pragma unroll
        for (int kt = 0; kt < 4; ++kt) fvc[kt] = fvn[kt];
    }
    __syncthreads();   // all fatt reads done before pmax overlay
    #pragma unroll
    for (int vt = 0; vt < 4; ++vt)
        #pragma unroll
        for (int r = 0; r < 4; ++r)
            s_fa[(lq * 32 + qsub * 16 + quad * 4 + r) * 72 + vt * 16 + m] = f2b_raw(mx[vt][r]);
    __syncthreads();

    // epilogue: t -> (q = t>>4 in [0,32), vg = t&15)
    {
        int q = t >> 4, vg = t & 15;
        int gq = qt2 * 32 + q;
        float gp = 0.f, ep = 0.f;
        #pragma unroll
        for (int jj = 0; jj < 4; ++jj) {
            int v = vg * 4 + jj;
            float mval = -1e30f;
            #pragma unroll
            for (int w = 0; w < 4; ++w)
                mval = fmaxf(mval, us2f(s_fa[(w * 32 + q) * 72 + v]));
            float qf = mval + ws[WS_QATT + (size_t)(b * LQ_ + gq) * 64 + v];
            gp += qf * LD<BF>(gatew, v);
            ep += qf * LD<BF>(valw, v);
        }
        #pragma unroll
        for (int off = 1; off <= 8; off <<= 1) {
            gp += __shfl_xor(gp, off, 64);
            ep += __shfl_xor(ep, off, 64);
        }
        if (vg == 0) {
            float qm = LD<BF>(qmask, b * LQ_ + gq);
            float g = (1.0f / (1.0f + expf(-gp))) * qm;
            ST<BF>(out, OUT_QFGATE + bwf * LQ_ + gq, g);
            ws[WS_E2 + bwf * LQ_ + gq] = expf(ep) * qm;
        }
    }

    // fused fragment self-attention (qt2==0 blocks; block-uniform branch)
    if (qt2 == 0) {
        if (t < 128) s_saw[t] = LD<BF>(saW, ((bwf >> 3) & 1) * 128 + t);
        __syncthreads();
        int l = t >> 3, j8 = t & 7;
        int swz = (l & 7) << 3;
        float p = 0.f;
        #pragma unroll
        for (int seg = 0; seg < 2; ++seg) {
            int koff = j8 * 16 + seg * 8;
            u32x4 fv = *(const u32x4*)&s_fp[l * 128 + (koff ^ swz)];
            const float* swp = &s_saw[koff];
            p += lo2f(fv.x) * swp[0] + hi2f(fv.x) * swp[1]
               + lo2f(fv.y) * swp[2] + hi2f(fv.y) * swp[3]
               + lo2f(fv.z) * swp[4] + hi2f(fv.z) * swp[5]
               + lo2f(fv.w) * swp[6] + hi2f(fv.w) * swp[7];
        }
        p += __shfl_xor(p, 1, 64);
        p += __shfl_xor(p, 2, 64);
        p += __shfl_xor(p, 4, 64);
        if (j8 == 0) s_att[l] = expf(p) * LD<BF>(fmask, bwf * LF_ + l);
        __syncthreads();
        if (t < 64) {
            float e = s_att[t], s = e;
            #pragma unroll
            for (int off = 1; off <= 32; off <<= 1) s += __shfl_xor(s, off, 64);
            float nrm = e / (s + 1e-7f);
            s_att[t] = nrm;
            ST<BF>(out, OUT_SELFATT + bwf * LF_ + t, nrm);
        }
        __syncthreads();
        int d = t & 127, grp = t >> 7;
        float fc = 0.f;
        #pragma unroll
        for (int li2 = 0; li2 < 16; ++li2) {
            int l2 = grp * 16 + li2;
            fc += us2f(s_fp[l2 * 128 + (d ^ ((l2 & 7) << 3))]) * s_att[l2];
        }
        s_tmp[grp * 128 + d] = fc;
        __syncthreads();
        if (t < 128)
            ST<BF>(out, OUT_FRAGCODE + bwf * D_ + t,
                   s_tmp[t] + s_tmp[128 + t] + s_tmp[256 + t] + s_tmp[384 + t]);
    }
}
__global__ __launch_bounds__(512) void k_qf(
    const void* saW, const void* fmask, const void* gatew, const void* valw,
    const void* qmask, float* ws, void* out)
{
    __shared__ char smem[37632];
    if (is_bf(qmask)) qf_body<true >(saW, fmask, gatew, valw, qmask, ws, out, smem);
    else              qf_body<false>(saW, fmask, gatew, valw, qmask, ws, out, smem);
}

// ================= K_qcode: e2 softmax over LQ + query_code ================
template<bool BF>
__device__ __forceinline__ void qcode_body(const float* ws, void* out,
                                           float* s_n, float* s_part)
{
    int bwf = blockIdx.x, b = bwf >> 4, t = threadIdx.x;
    float e = ws[WS_E2 + bwf * LQ_ + t];
    float s = e;
    #pragma unroll
    for (int off = 1; off <= 32; off <<= 1) s += __shfl_xor(s, off, 64);
    if ((t & 63) == 0) s_part[t >> 6] = s;
    __syncthreads();
    float tot = s_part[0] + s_part[1] + 1e-7f;
    s_n[t] = e / tot;
    __syncthreads();
    float qc = 0.f;
    #pragma unroll 8
    for (int q = 0; q < LQ_; ++q)
        qc += ws[WS_QP + (size_t)(b * LQ_ + q) * 128 + t] * s_n[q];
    ST<BF>(out, OUT_QUERYCODE + bwf * D_ + t, qc);
}
__global__ __launch_bounds__(128) void k_qcode(const void* qmask, const float* ws, void* out)
{
    __shared__ float s_n[LQ_];
    __shared__ float s_part[2];
    if (is_bf(qmask)) qcode_body<true >(ws, out, s_n, s_part);
    else              qcode_body<false>(ws, out, s_n, s_part);
}

extern "C" void kernel_launch(void* const* d_in, const int* in_sizes, int n_in,
                              void* d_out, int out_size, void* d_ws, size_t ws_size,
                              hipStream_t stream)
{
    const void* query    = d_in[0];
    const void* fragment = d_in[1];
    const void* qmask    = d_in[2];
    const void* fmask    = d_in[3];
    const void* projW    = d_in[4];
    const void* projB    = d_in[5];
    const void* saW      = d_in[6];
    const void* qattW    = d_in[7];
    const void* fattW    = d_in[8];
    const void* qfW      = d_in[9];
    const void* gatew    = d_in[10];
    const void* valw     = d_in[11];
    float* ws = (float*)d_ws;

    hipLaunchKernelGGL(k_prep, dim3(4), dim3(256), 0, stream,
                       projW, qattW, qfW, fattW, qmask, ws);
    hipLaunchKernelGGL(k_proj, dim3(288), dim3(256), 0, stream,
                       query, fragment, projB, qmask, ws, d_out);
    hipLaunchKernelGGL(k_qf, dim3(256), dim3(512), 0, stream,
                       saW, fmask, gatew, valw, qmask, ws, d_out);
    hipLaunchKernelGGL(k_qcode, dim3(B_ * NWF_), dim3(128), 0, stream,
                       qmask, ws, d_out);
}

// Round 6
// 113.685 us; speedup vs baseline: 3.0806x; 1.0049x over previous
//
#include <hip/hip_runtime.h>
#include <hip/hip_bf16.h>

#define B_   4
#define LQ_  128
#define LF_  64
#define NW_  2
#define NFR_ 8
#define E_   128
#define D_   128
#define V_   64
#define NWF_ (NW_*NFR_)            // 16
#define NROW_Q (B_*LQ_)            // 512
#define NROW_F (B_*NW_*NFR_*LF_)   // 4096

using bf16 = __hip_bfloat16;
typedef unsigned short u16;
typedef unsigned int   u32;
typedef __attribute__((ext_vector_type(8))) short  bf16x8;
typedef __attribute__((ext_vector_type(4))) float  f32x4;
typedef __attribute__((ext_vector_type(4))) u32    u32x4;

// ---- workspace layout (float-index units) ----
#define WS_QP    0          // [512][128] f32   65536
#define WS_QATT  65536      // [512][64]  f32   32768
#define WS_E2    98304      // [64][128]  f32    8192
#define WS_FP16  106496     // [64 tiles][8192] u16, PRE-SWIZZLED per-bwf tile
#define WS_W3T   368640     // [64][128]  u16 (qf_att_W^T)  4096 f
#define WS_WFT   372736     // [64][128]  u16 (f_att_W^T)   4096 f

// ---- out layout (element units; u16 if BF out else f32) ----
#define OUT_FRAGCODE  0       // (B,NW,NFR,D)   8192
#define OUT_QUERYCODE 8192    // (B,NW,NFR,D)   8192
#define OUT_SELFATT   16384   // (B,NW,NFR,LF)  4096
#define OUT_QFGATE    20480   // (B,16,LQ)      8192
#define OUT_QUERY     28672   // (B,LQ,D)       65536

__device__ __forceinline__ float us2f(u16 v) { return __uint_as_float((u32)v << 16); }
__device__ __forceinline__ float lo2f(u32 v) { return __uint_as_float(v << 16); }
__device__ __forceinline__ float hi2f(u32 v) { return __uint_as_float(v & 0xffff0000u); }
__device__ __forceinline__ u16 f2b_raw(float f) {
    u32 u = __float_as_uint(f);
    return (u16)((u + 0x7fffu + ((u >> 16) & 1u)) >> 16);
}
// truncating pack of two f32's bf16 parts into one u32 (1 v_perm)
__device__ __forceinline__ u32 pk2(float hi, float lo) {
    return __builtin_amdgcn_perm(__float_as_uint(hi), __float_as_uint(lo), 0x07060302u);
}
template<bool BF> __device__ __forceinline__ float LD(const void* p, int i) {
    return BF ? us2f(((const u16*)p)[i]) : ((const float*)p)[i];
}
template<bool BF> __device__ __forceinline__ void ST(void* p, int i, float v) {
    if (BF) ((u16*)p)[i] = f2b_raw(v); else ((float*)p)[i] = v;
}
template<bool BF> __device__ __forceinline__ u16 LDB(const void* p, int i) {
    return BF ? ((const u16*)p)[i] : f2b_raw(((const float*)p)[i]);
}
__device__ __forceinline__ bool is_bf(const void* qmask) {
    return ((const u16*)qmask)[0] == 0x3F80u;
}

// ================= K1: projection + q_att + W3/Wf transposes ===============
// blocks 0..255  : fragment rows [r*16, r*16+16) -> WS_FP16 (pre-swizzled bf16)
// blocks 256..287: query rows -> WS_QP (+OUT_QUERY) and q_att -> WS_QATT
// blocks 288/289 : transpose-convert qfW / fattW -> u16 [v][k]
template<bool BF>
__device__ __forceinline__ void proj_body(
    const void* query, const void* fragment, const void* projW, const void* projB,
    const void* qattW, const void* qfW, const void* fattW,
    float* ws, void* out, char* smem)
{
    int r = blockIdx.x, t = threadIdx.x;
    if (r >= 288) {
        const void* src = (r == 288) ? qfW : fattW;
        u16* dst = (u16*)(ws + ((r == 288) ? WS_W3T : WS_WFT));
        u16* stg = (u16*)smem;                 // [128][65]
        #pragma unroll
        for (int it = 0; it < 32; ++it) {
            int i = t + 256 * it;              // [k][v], 8192 elems
            stg[(i >> 6) * 65 + (i & 63)] = LDB<BF>(src, i);
        }
        __syncthreads();
        #pragma unroll
        for (int it = 0; it < 32; ++it) {
            int j = t + 256 * it;              // [v][k]
            dst[(j >> 7) * 128 + (j & 127)] = stg[(j & 127) * 65 + (j >> 7)];
        }
        return;
    }
    u16* s_y = (u16*)smem;                     // [16][132] (query blocks only)
    int lane = t & 63, wave = t >> 6, m = lane & 15, quad = lane >> 4;
    bool isq = (r >= 256);
    int base = isq ? (r - 256) * 16 : r * 16;
    const void* x = isq ? query : fragment;

    // A-fragments direct from global (rows are k-contiguous)
    bf16x8 af[4];
    #pragma unroll
    for (int kt = 0; kt < 4; ++kt) {
        int off = (base + m) * 128 + kt * 32 + quad * 8;
        if (BF) af[kt] = *(const bf16x8*)((const u16*)x + off);
        else {
            f32x4 a = *(const f32x4*)((const float*)x + off);
            f32x4 c = *(const f32x4*)((const float*)x + off + 4);
            u32x4 av;
            av.x = pk2(a.y, a.x); av.y = pk2(a.w, a.z);
            av.z = pk2(c.y, c.x); av.w = pk2(c.w, c.z);
            af[kt] = __builtin_bit_cast(bf16x8, av);
        }
    }
    // B-fragments via strided scalar loads from projW [k][n]
    int nt0 = wave * 2;
    f32x4 acc[2];
    #pragma unroll
    for (int i = 0; i < 2; ++i) {
        float bv = LD<BF>(projB, (nt0 + i) * 16 + m);
        acc[i] = (f32x4){bv, bv, bv, bv};
    }
    #pragma unroll
    for (int kt = 0; kt < 4; ++kt)
        #pragma unroll
        for (int i = 0; i < 2; ++i) {
            int n = (nt0 + i) * 16 + m, k0 = kt * 32 + quad * 8;
            short tmp[8];
            #pragma unroll
            for (int j = 0; j < 8; ++j)
                tmp[j] = (short)LDB<BF>(projW, (k0 + j) * 128 + n);
            bf16x8 bfr;
            #pragma unroll
            for (int j = 0; j < 8; ++j) bfr[j] = tmp[j];
            acc[i] = __builtin_amdgcn_mfma_f32_16x16x32_bf16(af[kt], bfr, acc[i], 0, 0, 0);
        }
    if (!isq) {
        // store pre-swizzled into the bwf tile
        u16* fp16 = (u16*)(ws + WS_FP16) + (size_t)(r >> 2) * 8192;
        #pragma unroll
        for (int i = 0; i < 2; ++i)
            #pragma unroll
            for (int rr = 0; rr < 4; ++rr) {
                int row = (r & 3) * 16 + quad * 4 + rr;
                int col = (nt0 + i) * 16 + m;
                fp16[row * 128 + (col ^ ((row & 7) << 3))] = f2b_raw(acc[i][rr]);
            }
    } else {
        #pragma unroll
        for (int i = 0; i < 2; ++i)
            #pragma unroll
            for (int rr = 0; rr < 4; ++rr) {
                int gr = base + quad * 4 + rr, col = (nt0 + i) * 16 + m;
                float v = acc[i][rr];
                ws[WS_QP + (size_t)gr * 128 + col] = v;
                ST<BF>(out, OUT_QUERY + gr * 128 + col, v);
                s_y[(quad * 4 + rr) * 132 + col] = f2b_raw(v);
            }
        __syncthreads();
        // q_att = Y @ qattW : A from LDS, B strided from qattW [k][v]
        bf16x8 ay[4];
        #pragma unroll
        for (int kt = 0; kt < 4; ++kt)
            ay[kt] = *(const bf16x8*)&s_y[m * 132 + kt * 32 + quad * 8];
        f32x4 a2 = (f32x4){0.f, 0.f, 0.f, 0.f};
        #pragma unroll
        for (int kt = 0; kt < 4; ++kt) {
            int v = wave * 16 + m, k0 = kt * 32 + quad * 8;
            short tmp[8];
            #pragma unroll
            for (int j = 0; j < 8; ++j)
                tmp[j] = (short)LDB<BF>(qattW, (k0 + j) * 64 + v);
            bf16x8 b2;
            #pragma unroll
            for (int j = 0; j < 8; ++j) b2[j] = tmp[j];
            a2 = __builtin_amdgcn_mfma_f32_16x16x32_bf16(ay[kt], b2, a2, 0, 0, 0);
        }
        #pragma unroll
        for (int rr = 0; rr < 4; ++rr)
            ws[WS_QATT + (size_t)(base + quad * 4 + rr) * 64 + wave * 16 + m] = a2[rr];
    }
}
__global__ __launch_bounds__(256) void k_proj(
    const void* query, const void* fragment, const void* projW, const void* projB,
    const void* qattW, const void* qfW, const void* fattW, const void* qmask,
    float* ws, void* out)
{
    __shared__ char smem[16640];
    if (is_bf(qmask)) proj_body<true >(query, fragment, projW, projB, qattW, qfW, fattW, ws, out, smem);
    else              proj_body<false>(query, fragment, projW, projB, qattW, qfW, fattW, ws, out, smem);
}

// ================= K2: MFMA qf pass, low-pressure ==========================
// 512 blocks (bwf, qt of 16 q) x 256 thr = 4 waves.
// wave = (lhalf = w>>1 owning 32 l, vhalf = w&1 owning vt pair).
// LDS: s_fp 16384 | s_fa u16[64][72] 9216 | s_pmax f32[2][16][68] 8704
//      | saw 512 | att 256 | tmp 512  = 35584 B  (4 blocks/CU)
template<bool BF>
__device__ __forceinline__ void qf_body(
    const void* saW, const void* fmask, const void* gatew, const void* valw,
    const void* qmask, float* ws, void* out, char* smem)
{
    u16*   s_fp   = (u16*)smem;
    u16*   s_fa   = (u16*)(smem + 16384);
    float* s_pmax = (float*)(smem + 25600);
    float* s_saw  = (float*)(smem + 34304);
    float* s_att  = (float*)(smem + 34816);
    float* s_tmp  = (float*)(smem + 35072);

    int t = threadIdx.x, lane = t & 63, wave = t >> 6;
    int bwf = blockIdx.x >> 3, qt = blockIdx.x & 7;
    int b = bwf >> 4;
    int m = lane & 15, quad = lane >> 4;
    int lhalf = wave >> 1, vhalf = wave & 1;

    // stage fp tile: straight contiguous copy (pre-swizzled in ws)
    {
        const u32* src = (const u32*)((const u16*)(ws + WS_FP16) + (size_t)bwf * 8192);
        u32* d32 = (u32*)s_fp;
        #pragma unroll
        for (int k = 0; k < 16; ++k) d32[t + 256 * k] = src[t + 256 * k];
    }
    __syncthreads();

    // f_att rows [wave*16, wave*16+16): stream wff one vt at a time (low regs)
    {
        int lr = wave * 16;
        const u16* wft = (const u16*)(ws + WS_WFT);
        bf16x8 afk[4];
        #pragma unroll
        for (int kt = 0; kt < 4; ++kt)
            afk[kt] = *(const bf16x8*)&s_fp[(lr + m) * 128 + ((kt * 32 + quad * 8) ^ ((m & 7) << 3))];
        #pragma unroll
        for (int vt = 0; vt < 4; ++vt) {
            f32x4 a0 = (f32x4){0.f, 0.f, 0.f, 0.f};
            #pragma unroll
            for (int kt = 0; kt < 4; ++kt) {
                bf16x8 wk = *(const bf16x8*)(wft + (vt * 16 + m) * 128 + kt * 32 + quad * 8);
                a0 = __builtin_amdgcn_mfma_f32_16x16x32_bf16(afk[kt], wk, a0, 0, 0, 0);
            }
            #pragma unroll
            for (int r = 0; r < 4; ++r)
                s_fa[(lr + quad * 4 + r) * 72 + vt * 16 + m] = f2b_raw(a0[r]);
        }
    }
    // qp fragments (f32, 32 regs)
    float qpreg[4][8];
    {
        const float* qprow = ws + WS_QP + (size_t)(b * LQ_ + qt * 16 + m) * 128;
        #pragma unroll
        for (int kt = 0; kt < 4; ++kt) {
            f32x4 x0 = *(const f32x4*)(qprow + kt * 32 + quad * 8);
            f32x4 x1 = *(const f32x4*)(qprow + kt * 32 + quad * 8 + 4);
            qpreg[kt][0] = x0.x; qpreg[kt][1] = x0.y; qpreg[kt][2] = x0.z; qpreg[kt][3] = x0.w;
            qpreg[kt][4] = x1.x; qpreg[kt][5] = x1.y; qpreg[kt][6] = x1.z; qpreg[kt][7] = x1.w;
        }
    }
    // W3 fragments for this wave's 2 vt (32 regs)
    bf16x8 w3f[2][4];
    {
        const u16* w3t = (const u16*)(ws + WS_W3T);
        #pragma unroll
        for (int i = 0; i < 2; ++i)
            #pragma unroll
            for (int kt = 0; kt < 4; ++kt)
                w3f[i][kt] = *(const bf16x8*)(w3t + ((vhalf * 2 + i) * 16 + m) * 128 + kt * 32 + quad * 8);
    }
    __syncthreads();   // f_att visible block-wide

    float mx[2][4];
    #pragma unroll
    for (int i = 0; i < 2; ++i)
        #pragma unroll
        for (int r = 0; r < 4; ++r) mx[i][r] = -1e30f;

    int lbase = lhalf * 32;
    #pragma unroll 2
    for (int li = 0; li < 32; ++li) {
        int l = lbase + li;
        int sw = (l & 7) << 3;
        bf16x8 af[4];
        #pragma unroll
        for (int kt = 0; kt < 4; ++kt) {
            u32x4 fv = *(const u32x4*)&s_fp[l * 128 + ((kt * 32 + quad * 8) ^ sw)];
            u32x4 av;
            av.x = pk2(qpreg[kt][1] * hi2f(fv.x), qpreg[kt][0] * lo2f(fv.x));
            av.y = pk2(qpreg[kt][3] * hi2f(fv.y), qpreg[kt][2] * lo2f(fv.y));
            av.z = pk2(qpreg[kt][5] * hi2f(fv.z), qpreg[kt][4] * lo2f(fv.z));
            av.w = pk2(qpreg[kt][7] * hi2f(fv.w), qpreg[kt][6] * lo2f(fv.w));
            af[kt] = __builtin_bit_cast(bf16x8, av);
        }
        #pragma unroll
        for (int i = 0; i < 2; ++i) {
            float fa = us2f(s_fa[l * 72 + (vhalf * 2 + i) * 16 + m]);
            f32x4 acc = (f32x4){fa, fa, fa, fa};
            #pragma unroll
            for (int kt = 0; kt < 4; ++kt)
                acc = __builtin_amdgcn_mfma_f32_16x16x32_bf16(af[kt], w3f[i][kt], acc, 0, 0, 0);
            #pragma unroll
            for (int r = 0; r < 4; ++r) mx[i][r] = fmaxf(mx[i][r], acc[r]);
        }
    }
    #pragma unroll
    for (int i = 0; i < 2; ++i)
        #pragma unroll
        for (int r = 0; r < 4; ++r)
            s_pmax[lhalf * 1088 + (quad * 4 + r) * 68 + (vhalf * 2 + i) * 16 + m] = mx[i][r];
    __syncthreads();

    // epilogue: t -> (q = t>>4 in [0,16), vg = t&15)
    {
        int q = t >> 4, vg = t & 15;
        int gq = qt * 16 + q;
        float gp = 0.f, ep = 0.f;
        #pragma unroll
        for (int jj = 0; jj < 4; ++jj) {
            int v = vg * 4 + jj;
            float mval = fmaxf(s_pmax[q * 68 + v], s_pmax[1088 + q * 68 + v]);
            float qf = mval + ws[WS_QATT + (size_t)(b * LQ_ + gq) * 64 + v];
            gp += qf * LD<BF>(gatew, v);
            ep += qf * LD<BF>(valw, v);
        }
        #pragma unroll
        for (int off = 1; off <= 8; off <<= 1) {
            gp += __shfl_xor(gp, off, 64);
            ep += __shfl_xor(ep, off, 64);
        }
        if (vg == 0) {
            float qm = LD<BF>(qmask, b * LQ_ + gq);
            float g = (1.0f / (1.0f + expf(-gp))) * qm;
            ST<BF>(out, OUT_QFGATE + bwf * LQ_ + gq, g);
            ws[WS_E2 + bwf * LQ_ + gq] = expf(ep) * qm;
        }
    }

    // fused fragment self-attention (qt==0 blocks; block-uniform branch)
    if (qt == 0) {
        if (t < 128) s_saw[t] = LD<BF>(saW, ((bwf >> 3) & 1) * 128 + t);
        __syncthreads();
        int l = t >> 2, j4 = t & 3;
        int swz = (l & 7) << 3;
        float p = 0.f;
        #pragma unroll
        for (int seg = 0; seg < 4; ++seg) {
            int koff = j4 * 32 + seg * 8;
            u32x4 fv = *(const u32x4*)&s_fp[l * 128 + (koff ^ swz)];
            const float* swp = &s_saw[koff];
            p += lo2f(fv.x) * swp[0] + hi2f(fv.x) * swp[1]
               + lo2f(fv.y) * swp[2] + hi2f(fv.y) * swp[3]
               + lo2f(fv.z) * swp[4] + hi2f(fv.z) * swp[5]
               + lo2f(fv.w) * swp[6] + hi2f(fv.w) * swp[7];
        }
        p += __shfl_xor(p, 1, 64);
        p += __shfl_xor(p, 2, 64);
        if (j4 == 0) s_att[l] = expf(p) * LD<BF>(fmask, bwf * LF_ + l);
        __syncthreads();
        if (t < 64) {
            float e = s_att[t], s = e;
            #pragma unroll
            for (int off = 1; off <= 32; off <<= 1) s += __shfl_xor(s, off, 64);
            float nrm = e / (s + 1e-7f);
            s_att[t] = nrm;
            ST<BF>(out, OUT_SELFATT + bwf * LF_ + t, nrm);
        }
        __syncthreads();
        int d = t & 127, half = t >> 7;
        float fc = 0.f;
        #pragma unroll
        for (int li2 = 0; li2 < 32; ++li2) {
            int l2 = half * 32 + li2;
            fc += us2f(s_fp[l2 * 128 + (d ^ ((l2 & 7) << 3))]) * s_att[l2];
        }
        if (half == 1) s_tmp[d] = fc;
        __syncthreads();
        if (half == 0) ST<BF>(out, OUT_FRAGCODE + bwf * D_ + d, fc + s_tmp[d]);
    }
}
__global__ __launch_bounds__(256, 4) void k_qf(
    const void* saW, const void* fmask, const void* gatew, const void* valw,
    const void* qmask, float* ws, void* out)
{
    __shared__ char smem[35584];
    if (is_bf(qmask)) qf_body<true >(saW, fmask, gatew, valw, qmask, ws, out, smem);
    else              qf_body<false>(saW, fmask, gatew, valw, qmask, ws, out, smem);
}

// ================= K3: e2 softmax over LQ + query_code =====================
template<bool BF>
__device__ __forceinline__ void qcode_body(const float* ws, void* out,
                                           float* s_n, float* s_part)
{
    int bwf = blockIdx.x, b = bwf >> 4, t = threadIdx.x;
    float e = ws[WS_E2 + bwf * LQ_ + t];
    float s = e;
    #pragma unroll
    for (int off = 1; off <= 32; off <<= 1) s += __shfl_xor(s, off, 64);
    if ((t & 63) == 0) s_part[t >> 6] = s;
    __syncthreads();
    float tot = s_part[0] + s_part[1] + 1e-7f;
    s_n[t] = e / tot;
    __syncthreads();
    float qc = 0.f;
    #pragma unroll 8
    for (int q = 0; q < LQ_; ++q)
        qc += ws[WS_QP + (size_t)(b * LQ_ + q) * 128 + t] * s_n[q];
    ST<BF>(out, OUT_QUERYCODE + bwf * D_ + t, qc);
}
__global__ __launch_bounds__(128) void k_qcode(const void* qmask, const float* ws, void* out)
{
    __shared__ float s_n[LQ_];
    __shared__ float s_part[2];
    if (is_bf(qmask)) qcode_body<true >(ws, out, s_n, s_part);
    else              qcode_body<false>(ws, out, s_n, s_part);
}

extern "C" void kernel_launch(void* const* d_in, const int* in_sizes, int n_in,
                              void* d_out, int out_size, void* d_ws, size_t ws_size,
                              hipStream_t stream)
{
    const void* query    = d_in[0];
    const void* fragment = d_in[1];
    const void* qmask    = d_in[2];
    const void* fmask    = d_in[3];
    const void* projW    = d_in[4];
    const void* projB    = d_in[5];
    const void* saW      = d_in[6];
    const void* qattW    = d_in[7];
    const void* fattW    = d_in[8];
    const void* qfW      = d_in[9];
    const void* gatew    = d_in[10];
    const void* valw     = d_in[11];
    float* ws = (float*)d_ws;

    hipLaunchKernelGGL(k_proj, dim3(290), dim3(256), 0, stream,
                       query, fragment, projW, projB, qattW, qfW, fattW, qmask, ws, d_out);
    hipLaunchKernelGGL(k_qf, dim3(512), dim3(256), 0, stream,
                       saW, fmask, gatew, valw, qmask, ws, d_out);
    hipLaunchKernelGGL(k_qcode, dim3(B_ * NWF_), dim3(128), 0, stream,
                       qmask, ws, d_out);
}